// Round 9
// baseline (295.079 us; speedup 1.0000x reference)
//
#include <hip/hip_runtime.h>

#define T_ 8
#define N_ 10000
#define E_ 160000
#define G_ 32
#define C_ 10
#define F_ 128

typedef _Float16 f16;
typedef _Float16 f16x2 __attribute__((ext_vector_type(2)));
typedef _Float16 f16x4 __attribute__((ext_vector_type(4)));
typedef _Float16 f16x8 __attribute__((ext_vector_type(8)));
typedef float floatx4 __attribute__((ext_vector_type(4)));

static constexpr int NSL = 16;                    // preproc slices per t
static constexpr int SLICE = E_ / NSL;            // 10000 edges per (t, slice)

// ---------------- workspace layout (bytes) ----------------
static constexpr size_t OFF_H2    = 0;          // f16 [80000][128] layer-2 output (pool input)
static constexpr size_t OFF_G     = 20480000;   // f16 [80000][128] G1 = x*W1, reused as G2 = H1'*W2
static constexpr size_t OFF_H1    = 40960000;   // f16 [80000][128] H1' = dinv*relu(layer1)
static constexpr size_t OFF_REC   = 61440000;   // int [T][E] src, grouped by dst
static constexpr size_t OFF_CNT   = 66560000;   // int [T][16][N] slice hist -> slice base (5.12 MB)
static constexpr size_t OFF_DINV  = 71680000;   // float [T][N]
static constexpr size_t OFF_RP    = 72000000;   // int [T][N+1]
static constexpr size_t OFF_CNTG  = 72320032;   // int [T*G]
static constexpr size_t OFF_BRP   = 72321056;   // int [T*G+1]
static constexpr size_t OFF_WP    = 72322112;   // f16 packed W1,W2 (2*16384), 16B-aligned
static constexpr size_t OFF_BLIST = 72387648;   // int [80000]
static constexpr size_t OFF_GPACK = 72707648;   // f16 4*49152 packed GRU weights
static constexpr size_t OFF_PART  = 73100864;   // float [256][8][128] pool partials
// end ~74.2 MB

// ---------------- fast gates (v_exp_f32 / v_rcp_f32, ~1 ulp) ----------------
__device__ __forceinline__ float sig_fast(float x) {
  return __builtin_amdgcn_rcpf(1.0f + __builtin_amdgcn_exp2f(-1.4426950408889634f * x));
}
__device__ __forceinline__ float tanh_fast(float x) {
  return 1.0f - 2.0f * __builtin_amdgcn_rcpf(1.0f + __builtin_amdgcn_exp2f(2.8853900817779268f * x));
}

// ---------------- fused phase 1: blocks 0..127 = hist (t,s), blocks 128..351 = weight pack ----------------
__global__ __launch_bounds__(1024) void prep0_kernel(const int* __restrict__ ei,
                                                     const int* __restrict__ batch,
                                                     int* __restrict__ cnt,
                                                     int* __restrict__ cntG,
                                                     const float* __restrict__ W1,
                                                     const float* __restrict__ W2,
                                                     f16* __restrict__ Wp,
                                                     const float* __restrict__ A0,
                                                     const float* __restrict__ A1,
                                                     const float* __restrict__ A2,
                                                     const float* __restrict__ A3,
                                                     f16* __restrict__ gp) {
  __shared__ int hL[N_];                        // 40 KB (hist blocks only)
  __shared__ int cL[G_];
  int b = blockIdx.x, tid = threadIdx.x;
  if (b >= 128) {
    // ---- pack role ----
    int idx = (b - 128) * 1024 + tid;           // < 224*1024 = 229376
    if (idx < 32768) {
      const float* W = (idx < 16384) ? W1 : W2;
      int l = idx & 16383;
      int j = l & 7, lane = (l >> 3) & 63, ct = (l >> 9) & 7, kc = (l >> 12) & 3;
      int k = kc * 32 + ((lane >> 4) & 3) * 8 + j;
      int n = ct * 16 + (lane & 15);
      Wp[idx] = (f16)W[k * 128 + n];
    } else {
      int gidx = idx - 32768;                   // < 196608
      int mat = gidx / 49152, l = gidx - mat * 49152;
      int j = l & 7, lane = (l >> 3) & 63, kc = (l >> 9) & 3, nt = l >> 11;
      int k = kc * 32 + ((lane >> 4) & 3) * 8 + j;
      int u = nt * 16 + (lane & 15);
      const float* W = (mat == 0) ? A0 : (mat == 1) ? A1 : (mat == 2) ? A2 : A3;
      gp[gidx] = (f16)W[u * 128 + k];
    }
    return;
  }
  // ---- hist role: one (t, s) slice per block ----
  int t = b & 7, s = b >> 3;                    // XCD-swizzled by t; s in 0..15
  for (int i = tid; i < N_; i += 1024) hL[i] = 0;
  if (tid < G_) cL[tid] = 0;
  __syncthreads();
  const int* dstp = ei + (size_t)t * 2 * E_ + E_ + s * SLICE;
  for (int e4 = tid; e4 < SLICE / 4; e4 += 1024) {
    int4 d = *(const int4*)(dstp + e4 * 4);
    atomicAdd(&hL[d.x], 1); atomicAdd(&hL[d.y], 1);
    atomicAdd(&hL[d.z], 1); atomicAdd(&hL[d.w], 1);
  }
  if (s == 0)
    for (int n = tid; n < N_; n += 1024) atomicAdd(&cL[batch[t * N_ + n]], 1);
  __syncthreads();
  int* cp = cnt + ((size_t)t * NSL + s) * N_;
  for (int i = tid; i < N_; i += 1024) cp[i] = hL[i];
  if (s == 0 && tid < G_) cntG[t * G_ + tid] = cL[tid];
}

// ---------------- phase 2: per-t scan -> rp, dinv, in-place slice bases; blk8 -> brp ----------------
__global__ __launch_bounds__(1024) void scan_kernel(int* __restrict__ cnt,
                                                    int* __restrict__ rp,
                                                    float* __restrict__ dinv,
                                                    const int* __restrict__ cntG,
                                                    int* __restrict__ brp) {
  __shared__ int wsum[16];
  __shared__ int carry;
  int t = blockIdx.x, tid = threadIdx.x, lane = tid & 63, wid = tid >> 6;
  if (t == 8) {
    int v = (tid < 256) ? cntG[tid] : 0;
    for (int ofs = 1; ofs < 64; ofs <<= 1) {
      int u = __shfl_up(v, ofs);
      if (lane >= ofs) v += u;
    }
    if (lane == 63 && wid < 4) wsum[wid] = v;
    __syncthreads();
    if (tid < 256) {
      int base = 0;
      for (int w = 0; w < wid; ++w) base += wsum[w];
      if (tid == 0) brp[0] = 0;
      brp[tid + 1] = v + base;
    }
    return;
  }
  if (tid == 0) { carry = 0; rp[t * (N_ + 1)] = 0; }
  __syncthreads();
  for (int c0 = 0; c0 < N_; c0 += 1024) {
    int n = c0 + tid;
    int vs[NSL];
    int deg = 0;
    if (n < N_) {
#pragma unroll
      for (int s = 0; s < NSL; ++s) {
        vs[s] = cnt[((size_t)t * NSL + s) * N_ + n];
        deg += vs[s];
      }
      dinv[t * N_ + n] = rsqrtf((float)deg + 1.0f);
    }
    int v = (n < N_) ? deg : 0;
    int v0 = v;
    for (int ofs = 1; ofs < 64; ofs <<= 1) {
      int u = __shfl_up(v, ofs);
      if (lane >= ofs) v += u;
    }
    if (lane == 63) wsum[wid] = v;
    __syncthreads();
    if (wid == 0) {
      int w = (lane < 16) ? wsum[lane] : 0;
      for (int ofs = 1; ofs < 16; ofs <<= 1) {
        int u = __shfl_up(w, ofs);
        if (lane >= ofs) w += u;
      }
      if (lane < 16) wsum[lane] = w;
    }
    __syncthreads();
    int base = carry + (wid ? wsum[wid - 1] : 0);
    if (n < N_) {
      rp[t * (N_ + 1) + n + 1] = base + v;
      int run = base + v - v0;
#pragma unroll
      for (int s = 0; s < NSL; ++s) {
        int vv = vs[s];
        cnt[((size_t)t * NSL + s) * N_ + n] = run;
        run += vv;
      }
    }
    __syncthreads();
    if (tid == 0) carry += wsum[15];
    __syncthreads();
  }
}

// ---------------- phase 3: per-(t,s) CSR placement via LDS running offsets + blist ----------------
__global__ __launch_bounds__(1024) void fill_kernel(const int* __restrict__ ei,
                                                    const int* __restrict__ base,
                                                    int* __restrict__ rec,
                                                    const int* __restrict__ batch,
                                                    const int* __restrict__ brp,
                                                    int* __restrict__ blist) {
  __shared__ int offL[N_];                      // 40 KB running offsets
  __shared__ int cb[G_];
  int b = blockIdx.x, tid = threadIdx.x;
  int t = b & 7, s = b >> 3;
  const int* bp = base + ((size_t)t * NSL + s) * N_;
  for (int i = tid; i < N_; i += 1024) offL[i] = bp[i];
  if (s == 0 && tid < G_) cb[tid] = brp[t * G_ + tid];
  __syncthreads();
  const int* srcp = ei + (size_t)t * 2 * E_ + s * SLICE;
  const int* dstp = srcp + E_;
  int* rt = rec + (size_t)t * E_;
  for (int e4 = tid; e4 < SLICE / 4; e4 += 1024) {
    int4 sv = *(const int4*)(srcp + e4 * 4);
    int4 dv = *(const int4*)(dstp + e4 * 4);
    int p0 = atomicAdd(&offL[dv.x], 1);
    int p1 = atomicAdd(&offL[dv.y], 1);
    int p2 = atomicAdd(&offL[dv.z], 1);
    int p3 = atomicAdd(&offL[dv.w], 1);
    rt[p0] = sv.x; rt[p1] = sv.y; rt[p2] = sv.z; rt[p3] = sv.w;
  }
  if (s == 0) {
    for (int n = tid; n < N_; n += 1024) {
      int g = batch[t * N_ + n];
      int p = atomicAdd(&cb[g], 1);
      blist[p] = t * N_ + n;
    }
  }
}

// ---------------- GEMM: O = A @ W (no epilogue). FP32A=1: A is fp32, cvt in-register ----------------
template <int FP32A>
__global__ __launch_bounds__(256) void gemm_kernel(const void* __restrict__ Ap,
                                                   const f16* __restrict__ Wp,
                                                   f16* __restrict__ O) {
  __shared__ f16x8 Bp[2048];                    // 32 KB packed W
  const f16x8* Wv = (const f16x8*)Wp;
  for (int i = threadIdx.x; i < 2048; i += 256) Bp[i] = Wv[i];
  __syncthreads();
  int wave = threadIdx.x >> 6, lane = threadIdx.x & 63;
  int quad = lane >> 4, m = lane & 15;
  int rowbase = blockIdx.x * 64 + wave * 16;
  floatx4 acc[8];
#pragma unroll
  for (int ct = 0; ct < 8; ++ct) { floatx4 z = {0.f, 0.f, 0.f, 0.f}; acc[ct] = z; }
#pragma unroll
  for (int kc = 0; kc < 4; ++kc) {
    f16x8 a;
    if (FP32A) {
      const float* Ar = (const float*)Ap + (size_t)(rowbase + m) * F_ + kc * 32 + quad * 8;
      float4 lo = *(const float4*)Ar;
      float4 hi = *(const float4*)(Ar + 4);
      a[0] = (f16)lo.x; a[1] = (f16)lo.y; a[2] = (f16)lo.z; a[3] = (f16)lo.w;
      a[4] = (f16)hi.x; a[5] = (f16)hi.y; a[6] = (f16)hi.z; a[7] = (f16)hi.w;
    } else {
      a = ((const f16x8*)((const f16*)Ap + (size_t)(rowbase + m) * F_))[kc * 4 + quad];
    }
#pragma unroll
    for (int ct = 0; ct < 8; ++ct)
      acc[ct] = __builtin_amdgcn_mfma_f32_16x16x32_f16(a, Bp[(kc * 8 + ct) * 64 + lane],
                                                       acc[ct], 0, 0, 0);
  }
#pragma unroll
  for (int ct = 0; ct < 8; ++ct) {
    int colc = ct * 16 + m;
#pragma unroll
    for (int r = 0; r < 4; ++r)
      O[(size_t)(rowbase + quad * 4 + r) * F_ + colc] = (f16)acc[ct][r];
  }
}

// ---------------- aggregation v6: gather G, 3-deep pipeline; L1: in-loop src dinv ----------------
// L1=1: s = Σ dinv[src]·G[src] + ds·G[row];  out = relu(ds·s + b)·ds   (H1', pre-scaled for layer 2)
// L1=0: s = Σ G'[src] + G'[row];             out = relu(ds·s + b)      (H2, pool input)
template <int L1>
__global__ __launch_bounds__(256) void agg_kernel(const f16* __restrict__ X, f16* __restrict__ O,
                                                  const int* __restrict__ rp,
                                                  const int* __restrict__ rec,
                                                  const float* __restrict__ dinv,
                                                  const float* __restrict__ bias) {
  int wave = threadIdx.x >> 6, lane = threadIdx.x & 63;
  int eg = lane >> 4;
  int cb = (lane & 15) * 8;
  int b = blockIdx.x;
  int t = b & 7, i = b >> 3;                    // t-swizzled: per-XCD L2 locality on G slice
  int n = i * 4 + wave;
  int row = t * N_ + n;
  float ds = dinv[row];
  int beg = rp[t * (N_ + 1) + n], end = rp[t * (N_ + 1) + n + 1];
  beg = __builtin_amdgcn_readfirstlane(beg);
  end = __builtin_amdgcn_readfirstlane(end);
  const int* rcb = rec + (size_t)t * E_ + beg + eg;
  const f16* Xt = X + (size_t)t * N_ * F_;
  const float* dt = dinv + t * N_;

  float s[8] = {0.f, 0.f, 0.f, 0.f, 0.f, 0.f, 0.f, 0.f};
  if (eg == 3) {                                // self-loop term on slot 3
    f16x8 v = *(const f16x8*)(Xt + (size_t)n * F_ + cb);
    float c = L1 ? ds : 1.0f;
#pragma unroll
    for (int j = 0; j < 8; ++j) s[j] += c * (float)v[j];
  }
  int cnt = end - beg;
  int nq = cnt >> 2;
  if (nq > 0) {
    // 4 indices prefetched, 3 value(+scale) loads in flight
    int rid0 = rcb[0];
    int rid1 = (nq > 1) ? rcb[4] : 0;
    int rid2 = (nq > 2) ? rcb[8] : 0;
    f16x8 vA = *(const f16x8*)(Xt + (size_t)rid0 * F_ + cb);
    float dvA = L1 ? dt[rid0] : 1.0f;
    f16x8 vB, vC;
    float dvB = 1.0f, dvC = 1.0f;
    if (nq > 1) { vB = *(const f16x8*)(Xt + (size_t)rid1 * F_ + cb); if (L1) dvB = dt[rid1]; }
    if (nq > 2) { vC = *(const f16x8*)(Xt + (size_t)rid2 * F_ + cb); if (L1) dvC = dt[rid2]; }
    int ridN = (nq > 3) ? rcb[12] : 0;
    for (int q = 0; q + 3 < nq; ++q) {
      f16x8 vD = *(const f16x8*)(Xt + (size_t)ridN * F_ + cb);
      float dvD = L1 ? dt[ridN] : 1.0f;
      int ridNN = rcb[(q + 4) * 4];             // ≤3 ints past segment: lands in ws, unused unless valid
#pragma unroll
      for (int j = 0; j < 8; ++j) s[j] += L1 ? dvA * (float)vA[j] : (float)vA[j];
      vA = vB; vB = vC; vC = vD; dvA = dvB; dvB = dvC; dvC = dvD; ridN = ridNN;
    }
#pragma unroll
    for (int j = 0; j < 8; ++j) s[j] += L1 ? dvA * (float)vA[j] : (float)vA[j];
    if (nq > 1) {
#pragma unroll
      for (int j = 0; j < 8; ++j) s[j] += L1 ? dvB * (float)vB[j] : (float)vB[j];
    }
    if (nq > 2) {
#pragma unroll
      for (int j = 0; j < 8; ++j) s[j] += L1 ? dvC * (float)vC[j] : (float)vC[j];
    }
  }
  int rem = cnt & 3;
  if (eg < rem) {                               // tail: slots 0..rem-1
    int rid = rcb[nq * 4];
    f16x8 v = *(const f16x8*)(Xt + (size_t)rid * F_ + cb);
    float dv = L1 ? dt[rid] : 1.0f;
#pragma unroll
    for (int j = 0; j < 8; ++j) s[j] += L1 ? dv * (float)v[j] : (float)v[j];
  }
#pragma unroll
  for (int j = 0; j < 8; ++j) {                 // reduce the 4 edge slots
    s[j] += __shfl_xor(s[j], 16);
    s[j] += __shfl_xor(s[j], 32);
  }
  if (eg == 0) {
    float4 b0 = *(const float4*)(bias + cb);
    float4 b1v = *(const float4*)(bias + cb + 4);
    float bb[8] = {b0.x, b0.y, b0.z, b0.w, b1v.x, b1v.y, b1v.z, b1v.w};
    f16x8 o;
#pragma unroll
    for (int j = 0; j < 8; ++j) {
      float v = fmaxf(ds * s[j] + bb[j], 0.0f);
      if (L1) v *= ds;
      o[j] = (f16)v;
    }
    *(f16x8*)(O + (size_t)row * F_ + cb) = o;
  }
}

// ---------------- pool stage 1: one wave per (group, 1/8 slice) -> fp32 partials ----------------
__global__ void pool1_kernel(const f16* __restrict__ H, const int* __restrict__ brp,
                             const int* __restrict__ blist, float* __restrict__ part) {
  int b = blockIdx.x;                           // 512
  int wave = threadIdx.x >> 6, lane = threadIdx.x & 63;
  int idx = b >> 1;                             // t*G+g
  int s = (b & 1) * 4 + wave;                   // 0..7
  int beg = brp[idx], end = brp[idx + 1];
  beg = __builtin_amdgcn_readfirstlane(beg);
  end = __builtin_amdgcn_readfirstlane(end);
  int len = end - beg;
  int lo = beg + (int)(((long long)len * s) >> 3);
  int hi = beg + (int)(((long long)len * (s + 1)) >> 3);
  float a00 = 0.f, a01 = 0.f, a10 = 0.f, a11 = 0.f;
  float a20 = 0.f, a21 = 0.f, a30 = 0.f, a31 = 0.f;
  int e = lo;
  for (; e + 3 < hi; e += 4) {
    int r0 = blist[e], r1 = blist[e + 1], r2 = blist[e + 2], r3 = blist[e + 3];
    f16x2 v0 = *(const f16x2*)(H + (size_t)r0 * F_ + 2 * lane);
    f16x2 v1 = *(const f16x2*)(H + (size_t)r1 * F_ + 2 * lane);
    f16x2 v2 = *(const f16x2*)(H + (size_t)r2 * F_ + 2 * lane);
    f16x2 v3 = *(const f16x2*)(H + (size_t)r3 * F_ + 2 * lane);
    a00 += (float)v0.x; a01 += (float)v0.y;
    a10 += (float)v1.x; a11 += (float)v1.y;
    a20 += (float)v2.x; a21 += (float)v2.y;
    a30 += (float)v3.x; a31 += (float)v3.y;
  }
  for (; e < hi; ++e) {
    int r = blist[e];
    f16x2 v = *(const f16x2*)(H + (size_t)r * F_ + 2 * lane);
    a00 += (float)v.x; a01 += (float)v.y;
  }
  float2 o;
  o.x = (a00 + a10) + (a20 + a30);
  o.y = (a01 + a11) + (a21 + a31);
  *(float2*)(part + ((size_t)idx * 8 + s) * F_ + 2 * lane) = o;
}

// ---------------- mega tail: pool2 + gi0 + 2-layer GRU + final linear (16 blocks) ----------------
__global__ __launch_bounds__(256, 1) void gru_mega(
    const f16* __restrict__ gp, const float* __restrict__ part,
    const int* __restrict__ brp,
    const float* __restrict__ bih0, const float* __restrict__ bhh0,
    const float* __restrict__ bih1, const float* __restrict__ bhh1,
    const float* __restrict__ Wc, const float* __restrict__ bc,
    float* __restrict__ out) {
  __shared__ f16 emb_l[16][136];                // rows r = t*2+g2 for this block's 2 groups
  __shared__ float gib0[16][384];               // gi0 for all 8 t, 2 groups
  __shared__ f16 hb0[16 * 136];
  __shared__ f16 hb1[16 * 136];
  __shared__ float ghb[2 * 384];
  __shared__ float gib[2 * 384];
  __shared__ float h1s[2 * 128];
  int tid = threadIdx.x, wave = tid >> 6, lane = tid & 63;
  int quad = lane >> 4, mm = lane & 15;
  int g2 = tid >> 7, f = tid & 127;
  int bid = blockIdx.x;

  // ---- stage A: reduce pool partials -> mean -> f16 emb ----
  {
    int r = tid >> 4;                           // 0..15 = t*2+g2
    int fb = (tid & 15) * 8;
    int idx = (r >> 1) * G_ + bid * 2 + (r & 1);
    float s[8] = {0.f, 0.f, 0.f, 0.f, 0.f, 0.f, 0.f, 0.f};
#pragma unroll
    for (int k = 0; k < 8; ++k) {
      const float* p = part + ((size_t)idx * 8 + k) * F_ + fb;
      float4 v0 = *(const float4*)p;
      float4 v1 = *(const float4*)(p + 4);
      s[0] += v0.x; s[1] += v0.y; s[2] += v0.z; s[3] += v0.w;
      s[4] += v1.x; s[5] += v1.y; s[6] += v1.z; s[7] += v1.w;
    }
    float d = fmaxf((float)(brp[idx + 1] - brp[idx]), 1.0f);
    f16x8 ev;
#pragma unroll
    for (int j = 0; j < 8; ++j) ev[j] = (f16)(s[j] / d);
    *(f16x8*)(&emb_l[r][fb]) = ev;
  }
  __syncthreads();

  // ---- stage B: gi0 = emb @ Wih0^T, 16 rows x 384 cols, into LDS ----
  {
    floatx4 acc[6];
#pragma unroll
    for (int i = 0; i < 6; ++i) { floatx4 z = {0.f, 0.f, 0.f, 0.f}; acc[i] = z; }
#pragma unroll
    for (int kc = 0; kc < 4; ++kc) {
      f16x8 a = *(const f16x8*)(&emb_l[mm][kc * 32 + quad * 8]);
#pragma unroll
      for (int i = 0; i < 6; ++i) {
        int nt = wave * 6 + i;
        f16x8 bf = *(const f16x8*)(gp + (size_t)((nt * 4 + kc) * 64 + lane) * 8);
        acc[i] = __builtin_amdgcn_mfma_f32_16x16x32_f16(a, bf, acc[i], 0, 0, 0);
      }
    }
#pragma unroll
    for (int i = 0; i < 6; ++i)
#pragma unroll
      for (int r = 0; r < 4; ++r)
        gib0[quad * 4 + r][(wave * 6 + i) * 16 + mm] = acc[i][r];
  }

  // ---- persistent recurrent weight fragments ----
  f16x8 B0[24], B1[24];
#pragma unroll
  for (int i = 0; i < 6; ++i)
#pragma unroll
    for (int kc = 0; kc < 4; ++kc) {
      size_t off = (size_t)((((wave * 6 + i) * 4 + kc) * 64 + lane)) * 8;
      B0[i * 4 + kc] = *(const f16x8*)(gp + 1 * 49152 + off);
      B1[i * 4 + kc] = *(const f16x8*)(gp + 3 * 49152 + off);
    }
  float br0 = bih0[f] + bhh0[f];
  float bz0 = bih0[128 + f] + bhh0[128 + f];
  float bni0 = bih0[256 + f], bnh0 = bhh0[256 + f];
  float br1 = bih1[f] + bhh1[f];
  float bz1 = bih1[128 + f] + bhh1[128 + f];
  float bni1 = bih1[256 + f], bnh1 = bhh1[256 + f];

  for (int i = tid; i < 16 * 136; i += 256) { hb0[i] = (f16)0.f; hb1[i] = (f16)0.f; }
  float h0 = 0.f, h1 = 0.f;
  __syncthreads();                              // covers gib0 writes + hb inits

  const f16* wih1 = gp + 2 * 49152;
  for (int t = 0; t < T_; ++t) {
    f16x8 Bs[24];
#pragma unroll
    for (int i = 0; i < 6; ++i)
#pragma unroll
      for (int kc = 0; kc < 4; ++kc)
        Bs[i * 4 + kc] = *(const f16x8*)(wih1 +
            (size_t)((((wave * 6 + i) * 4 + kc) * 64 + lane)) * 8);
    const float* gi = &gib0[t * 2 + g2][0];
    float gir = gi[f], giz = gi[128 + f], gin = gi[256 + f];

    floatx4 acc[6];
#pragma unroll
    for (int i = 0; i < 6; ++i) { floatx4 z = {0.f, 0.f, 0.f, 0.f}; acc[i] = z; }
#pragma unroll
    for (int kc = 0; kc < 4; ++kc) {
      f16x8 a = *(const f16x8*)(hb0 + mm * 136 + kc * 32 + quad * 8);
#pragma unroll
      for (int i = 0; i < 6; ++i)
        acc[i] = __builtin_amdgcn_mfma_f32_16x16x32_f16(a, B0[i * 4 + kc], acc[i], 0, 0, 0);
    }
    if (quad == 0) {
#pragma unroll
      for (int i = 0; i < 6; ++i) {
        ghb[0 * 384 + wave * 96 + i * 16 + mm] = acc[i][0];
        ghb[1 * 384 + wave * 96 + i * 16 + mm] = acc[i][1];
      }
    }
    __syncthreads();

    {
      float hr = ghb[g2 * 384 + f];
      float hz = ghb[g2 * 384 + 128 + f];
      float hn = ghb[g2 * 384 + 256 + f];
      float r = sig_fast(gir + hr + br0);
      float z = sig_fast(giz + hz + bz0);
      float nn = tanh_fast(gin + bni0 + r * (hn + bnh0));
      h0 = (1.0f - z) * nn + z * h0;
      hb0[g2 * 136 + f] = (f16)h0;
    }
    __syncthreads();

    floatx4 accx[6], acch[6];
#pragma unroll
    for (int i = 0; i < 6; ++i) {
      floatx4 z = {0.f, 0.f, 0.f, 0.f}; accx[i] = z; acch[i] = z;
    }
#pragma unroll
    for (int kc = 0; kc < 4; ++kc) {
      f16x8 ax = *(const f16x8*)(hb0 + mm * 136 + kc * 32 + quad * 8);
      f16x8 ah = *(const f16x8*)(hb1 + mm * 136 + kc * 32 + quad * 8);
#pragma unroll
      for (int i = 0; i < 6; ++i) {
        accx[i] = __builtin_amdgcn_mfma_f32_16x16x32_f16(ax, Bs[i * 4 + kc], accx[i], 0, 0, 0);
        acch[i] = __builtin_amdgcn_mfma_f32_16x16x32_f16(ah, B1[i * 4 + kc], acch[i], 0, 0, 0);
      }
    }
    if (quad == 0) {
#pragma unroll
      for (int i = 0; i < 6; ++i) {
        gib[0 * 384 + wave * 96 + i * 16 + mm] = accx[i][0];
        gib[1 * 384 + wave * 96 + i * 16 + mm] = accx[i][1];
        ghb[0 * 384 + wave * 96 + i * 16 + mm] = acch[i][0];
        ghb[1 * 384 + wave * 96 + i * 16 + mm] = acch[i][1];
      }
    }
    __syncthreads();

    {
      float i1r = gib[g2 * 384 + f];
      float i1z = gib[g2 * 384 + 128 + f];
      float i1n = gib[g2 * 384 + 256 + f];
      float hr = ghb[g2 * 384 + f];
      float hz = ghb[g2 * 384 + 128 + f];
      float hn = ghb[g2 * 384 + 256 + f];
      float r = sig_fast(i1r + hr + br1);
      float z = sig_fast(i1z + hz + bz1);
      float nn = tanh_fast(i1n + bni1 + r * (hn + bnh1));
      h1 = (1.0f - z) * nn + z * h1;
      hb1[g2 * 136 + f] = (f16)h1;
    }
    __syncthreads();
  }

  h1s[g2 * 128 + f] = h1;
  __syncthreads();
  if (tid < 2 * C_) {
    int gg = tid / C_, c = tid - gg * C_;
    float s = bc[c];
    const float* wr = Wc + (size_t)c * 128;
    const float* hr = h1s + gg * 128;
    for (int k = 0; k < 128; k += 4) {
      float4 w = *(const float4*)(wr + k);
      s += hr[k] * w.x + hr[k + 1] * w.y + hr[k + 2] * w.z + hr[k + 3] * w.w;
    }
    out[(bid * 2 + gg) * C_ + c] = s;
  }
}

extern "C" void kernel_launch(void* const* d_in, const int* in_sizes, int n_in,
                              void* d_out, int out_size, void* d_ws, size_t ws_size,
                              hipStream_t stream) {
  const float* x    = (const float*)d_in[0];
  const int*   ei   = (const int*)d_in[1];
  const int*   batch= (const int*)d_in[2];
  const float* W1   = (const float*)d_in[3];
  const float* b1   = (const float*)d_in[4];
  const float* W2   = (const float*)d_in[5];
  const float* b2   = (const float*)d_in[6];
  const float* Wih0 = (const float*)d_in[7];
  const float* Whh0 = (const float*)d_in[8];
  const float* bih0 = (const float*)d_in[9];
  const float* bhh0 = (const float*)d_in[10];
  const float* Wih1 = (const float*)d_in[11];
  const float* Whh1 = (const float*)d_in[12];
  const float* bih1 = (const float*)d_in[13];
  const float* bhh1 = (const float*)d_in[14];
  const float* Wc   = (const float*)d_in[15];
  const float* bc   = (const float*)d_in[16];
  float* out = (float*)d_out;

  char* ws = (char*)d_ws;
  f16*   H2    = (f16*)(ws + OFF_H2);
  f16*   G     = (f16*)(ws + OFF_G);   // G1 = x*W1; reused as G2 = H1'*W2
  f16*   H1p   = (f16*)(ws + OFF_H1);
  int*   rec   = (int*)(ws + OFF_REC);
  int*   cnt   = (int*)(ws + OFF_CNT);
  float* dinv  = (float*)(ws + OFF_DINV);
  int*   rp    = (int*)(ws + OFF_RP);
  int*   cntG  = (int*)(ws + OFF_CNTG);
  int*   brp   = (int*)(ws + OFF_BRP);
  f16*   Wp    = (f16*)(ws + OFF_WP);
  int*   blist = (int*)(ws + OFF_BLIST);
  f16*   gp    = (f16*)(ws + OFF_GPACK);
  float* part  = (float*)(ws + OFF_PART);

  prep0_kernel<<<352, 1024, 0, stream>>>(ei, batch, cnt, cntG,
                                         W1, W2, Wp, Wih0, Whh0, Wih1, Whh1, gp);
  // G1 = x*W1 (fp32 read, f16 cvt in-register) — no preproc dependency
  gemm_kernel<1><<<1250, 256, 0, stream>>>(x, Wp, G);
  scan_kernel<<<9, 1024, 0, stream>>>(cnt, rp, dinv, cntG, brp);
  fill_kernel<<<128, 1024, 0, stream>>>(ei, cnt, rec, batch, brp, blist);

  agg_kernel<1><<<20000, 256, 0, stream>>>(G, H1p, rp, rec, dinv, b1);
  gemm_kernel<0><<<1250, 256, 0, stream>>>(H1p, Wp + 16384, G);
  agg_kernel<0><<<20000, 256, 0, stream>>>(G, H2, rp, rec, dinv, b2);

  pool1_kernel<<<512, 256, 0, stream>>>(H2, brp, blist, part);
  gru_mega<<<16, 256, 0, stream>>>(gp, part, brp, bih0, bhh0, bih1, bhh1, Wc, bc, out);
}

// Round 10
// 294.930 us; speedup vs baseline: 1.0005x; 1.0005x over previous
//
#include <hip/hip_runtime.h>

#define T_ 8
#define N_ 10000
#define E_ 160000
#define G_ 32
#define C_ 10
#define F_ 128

typedef _Float16 f16;
typedef _Float16 f16x2 __attribute__((ext_vector_type(2)));
typedef _Float16 f16x4 __attribute__((ext_vector_type(4)));
typedef _Float16 f16x8 __attribute__((ext_vector_type(8)));
typedef float floatx4 __attribute__((ext_vector_type(4)));

static constexpr int NSL = 16;                    // preproc slices per t
static constexpr int SLICE = E_ / NSL;            // 10000 edges per (t, slice)

// ---------------- workspace layout (bytes) ----------------
static constexpr size_t OFF_H2    = 0;          // f16 [80000][128] layer-2 output (pool input)
static constexpr size_t OFF_G     = 20480000;   // f16 [80000][128] G1' = dinv*(x*W1), reused as G2 = H1'*W2
static constexpr size_t OFF_H1    = 40960000;   // f16 [80000][128] H1' = dinv*relu(layer1)
static constexpr size_t OFF_REC   = 61440000;   // int [T][E] src, grouped by dst
static constexpr size_t OFF_CNT   = 66560000;   // int [T][16][N] slice hist -> slice base (5.12 MB)
static constexpr size_t OFF_DINV  = 71680000;   // float [T][N]
static constexpr size_t OFF_RP    = 72000000;   // int [T][N+1]
static constexpr size_t OFF_CNTG  = 72320032;   // int [T*G]
static constexpr size_t OFF_BRP   = 72321056;   // int [T*G+1]
static constexpr size_t OFF_WP    = 72322112;   // f16 packed W1,W2 (2*16384), 16B-aligned
static constexpr size_t OFF_BLIST = 72387648;   // int [80000]
static constexpr size_t OFF_GPACK = 72707648;   // f16 4*49152 packed GRU weights
static constexpr size_t OFF_PART  = 73100864;   // float [256][8][128] pool partials
// end ~74.2 MB

// ---------------- fast gates (v_exp_f32 / v_rcp_f32, ~1 ulp) ----------------
__device__ __forceinline__ float sig_fast(float x) {
  return __builtin_amdgcn_rcpf(1.0f + __builtin_amdgcn_exp2f(-1.4426950408889634f * x));
}
__device__ __forceinline__ float tanh_fast(float x) {
  return 1.0f - 2.0f * __builtin_amdgcn_rcpf(1.0f + __builtin_amdgcn_exp2f(2.8853900817779268f * x));
}

// ---------------- fused phase 1: blocks 0..127 = hist (t,s), blocks 128..351 = weight pack ----------------
__global__ __launch_bounds__(1024) void prep0_kernel(const int* __restrict__ ei,
                                                     const int* __restrict__ batch,
                                                     int* __restrict__ cnt,
                                                     int* __restrict__ cntG,
                                                     const float* __restrict__ W1,
                                                     const float* __restrict__ W2,
                                                     f16* __restrict__ Wp,
                                                     const float* __restrict__ A0,
                                                     const float* __restrict__ A1,
                                                     const float* __restrict__ A2,
                                                     const float* __restrict__ A3,
                                                     f16* __restrict__ gp) {
  __shared__ int hL[N_];                        // 40 KB (hist blocks only)
  __shared__ int cL[G_];
  int b = blockIdx.x, tid = threadIdx.x;
  if (b >= 128) {
    // ---- pack role ----
    int idx = (b - 128) * 1024 + tid;           // < 224*1024 = 229376
    if (idx < 32768) {
      const float* W = (idx < 16384) ? W1 : W2;
      int l = idx & 16383;
      int j = l & 7, lane = (l >> 3) & 63, ct = (l >> 9) & 7, kc = (l >> 12) & 3;
      int k = kc * 32 + ((lane >> 4) & 3) * 8 + j;
      int n = ct * 16 + (lane & 15);
      Wp[idx] = (f16)W[k * 128 + n];
    } else {
      int gidx = idx - 32768;                   // < 196608
      int mat = gidx / 49152, l = gidx - mat * 49152;
      int j = l & 7, lane = (l >> 3) & 63, kc = (l >> 9) & 3, nt = l >> 11;
      int k = kc * 32 + ((lane >> 4) & 3) * 8 + j;
      int u = nt * 16 + (lane & 15);
      const float* W = (mat == 0) ? A0 : (mat == 1) ? A1 : (mat == 2) ? A2 : A3;
      gp[gidx] = (f16)W[u * 128 + k];
    }
    return;
  }
  // ---- hist role: one (t, s) slice per block ----
  int t = b & 7, s = b >> 3;                    // XCD-swizzled by t; s in 0..15
  for (int i = tid; i < N_; i += 1024) hL[i] = 0;
  if (tid < G_) cL[tid] = 0;
  __syncthreads();
  const int* dstp = ei + (size_t)t * 2 * E_ + E_ + s * SLICE;
  for (int e4 = tid; e4 < SLICE / 4; e4 += 1024) {
    int4 d = *(const int4*)(dstp + e4 * 4);
    atomicAdd(&hL[d.x], 1); atomicAdd(&hL[d.y], 1);
    atomicAdd(&hL[d.z], 1); atomicAdd(&hL[d.w], 1);
  }
  if (s == 0)
    for (int n = tid; n < N_; n += 1024) atomicAdd(&cL[batch[t * N_ + n]], 1);
  __syncthreads();
  int* cp = cnt + ((size_t)t * NSL + s) * N_;
  for (int i = tid; i < N_; i += 1024) cp[i] = hL[i];
  if (s == 0 && tid < G_) cntG[t * G_ + tid] = cL[tid];
}

// ---------------- phase 2: per-t scan -> rp, dinv, in-place slice bases; blk8 -> brp ----------------
__global__ __launch_bounds__(1024) void scan_kernel(int* __restrict__ cnt,
                                                    int* __restrict__ rp,
                                                    float* __restrict__ dinv,
                                                    const int* __restrict__ cntG,
                                                    int* __restrict__ brp) {
  __shared__ int wsum[16];
  __shared__ int carry;
  int t = blockIdx.x, tid = threadIdx.x, lane = tid & 63, wid = tid >> 6;
  if (t == 8) {
    int v = (tid < 256) ? cntG[tid] : 0;
    for (int ofs = 1; ofs < 64; ofs <<= 1) {
      int u = __shfl_up(v, ofs);
      if (lane >= ofs) v += u;
    }
    if (lane == 63 && wid < 4) wsum[wid] = v;
    __syncthreads();
    if (tid < 256) {
      int base = 0;
      for (int w = 0; w < wid; ++w) base += wsum[w];
      if (tid == 0) brp[0] = 0;
      brp[tid + 1] = v + base;
    }
    return;
  }
  if (tid == 0) { carry = 0; rp[t * (N_ + 1)] = 0; }
  __syncthreads();
  for (int c0 = 0; c0 < N_; c0 += 1024) {
    int n = c0 + tid;
    int vs[NSL];
    int deg = 0;
    if (n < N_) {
#pragma unroll
      for (int s = 0; s < NSL; ++s) {
        vs[s] = cnt[((size_t)t * NSL + s) * N_ + n];
        deg += vs[s];
      }
      dinv[t * N_ + n] = rsqrtf((float)deg + 1.0f);
    }
    int v = (n < N_) ? deg : 0;
    int v0 = v;
    for (int ofs = 1; ofs < 64; ofs <<= 1) {
      int u = __shfl_up(v, ofs);
      if (lane >= ofs) v += u;
    }
    if (lane == 63) wsum[wid] = v;
    __syncthreads();
    if (wid == 0) {
      int w = (lane < 16) ? wsum[lane] : 0;
      for (int ofs = 1; ofs < 16; ofs <<= 1) {
        int u = __shfl_up(w, ofs);
        if (lane >= ofs) w += u;
      }
      if (lane < 16) wsum[lane] = w;
    }
    __syncthreads();
    int base = carry + (wid ? wsum[wid - 1] : 0);
    if (n < N_) {
      rp[t * (N_ + 1) + n + 1] = base + v;
      int run = base + v - v0;
#pragma unroll
      for (int s = 0; s < NSL; ++s) {
        int vv = vs[s];
        cnt[((size_t)t * NSL + s) * N_ + n] = run;
        run += vv;
      }
    }
    __syncthreads();
    if (tid == 0) carry += wsum[15];
    __syncthreads();
  }
}

// ---------------- phase 3: per-(t,s) CSR placement via LDS running offsets + blist ----------------
__global__ __launch_bounds__(1024) void fill_kernel(const int* __restrict__ ei,
                                                    const int* __restrict__ base,
                                                    int* __restrict__ rec,
                                                    const int* __restrict__ batch,
                                                    const int* __restrict__ brp,
                                                    int* __restrict__ blist) {
  __shared__ int offL[N_];                      // 40 KB running offsets
  __shared__ int cb[G_];
  int b = blockIdx.x, tid = threadIdx.x;
  int t = b & 7, s = b >> 3;
  const int* bp = base + ((size_t)t * NSL + s) * N_;
  for (int i = tid; i < N_; i += 1024) offL[i] = bp[i];
  if (s == 0 && tid < G_) cb[tid] = brp[t * G_ + tid];
  __syncthreads();
  const int* srcp = ei + (size_t)t * 2 * E_ + s * SLICE;
  const int* dstp = srcp + E_;
  int* rt = rec + (size_t)t * E_;
  for (int e4 = tid; e4 < SLICE / 4; e4 += 1024) {
    int4 sv = *(const int4*)(srcp + e4 * 4);
    int4 dv = *(const int4*)(dstp + e4 * 4);
    int p0 = atomicAdd(&offL[dv.x], 1);
    int p1 = atomicAdd(&offL[dv.y], 1);
    int p2 = atomicAdd(&offL[dv.z], 1);
    int p3 = atomicAdd(&offL[dv.w], 1);
    rt[p0] = sv.x; rt[p1] = sv.y; rt[p2] = sv.z; rt[p3] = sv.w;
  }
  if (s == 0) {
    for (int n = tid; n < N_; n += 1024) {
      int g = batch[t * N_ + n];
      int p = atomicAdd(&cb[g], 1);
      blist[p] = t * N_ + n;
    }
  }
}

// ---------------- GEMM: O = [scale_row *] (A @ W). FP32A=1: A fp32, cvt in-register ----------------
template <int FP32A>
__global__ __launch_bounds__(256) void gemm_kernel(const void* __restrict__ Ap,
                                                   const f16* __restrict__ Wp,
                                                   f16* __restrict__ O,
                                                   const float* __restrict__ scale) {
  __shared__ f16x8 Bp[2048];                    // 32 KB packed W
  const f16x8* Wv = (const f16x8*)Wp;
  for (int i = threadIdx.x; i < 2048; i += 256) Bp[i] = Wv[i];
  __syncthreads();
  int wave = threadIdx.x >> 6, lane = threadIdx.x & 63;
  int quad = lane >> 4, m = lane & 15;
  int rowbase = blockIdx.x * 64 + wave * 16;
  floatx4 acc[8];
#pragma unroll
  for (int ct = 0; ct < 8; ++ct) { floatx4 z = {0.f, 0.f, 0.f, 0.f}; acc[ct] = z; }
#pragma unroll
  for (int kc = 0; kc < 4; ++kc) {
    f16x8 a;
    if (FP32A) {
      const float* Ar = (const float*)Ap + (size_t)(rowbase + m) * F_ + kc * 32 + quad * 8;
      float4 lo = *(const float4*)Ar;
      float4 hi = *(const float4*)(Ar + 4);
      a[0] = (f16)lo.x; a[1] = (f16)lo.y; a[2] = (f16)lo.z; a[3] = (f16)lo.w;
      a[4] = (f16)hi.x; a[5] = (f16)hi.y; a[6] = (f16)hi.z; a[7] = (f16)hi.w;
    } else {
      a = ((const f16x8*)((const f16*)Ap + (size_t)(rowbase + m) * F_))[kc * 4 + quad];
    }
#pragma unroll
    for (int ct = 0; ct < 8; ++ct)
      acc[ct] = __builtin_amdgcn_mfma_f32_16x16x32_f16(a, Bp[(kc * 8 + ct) * 64 + lane],
                                                       acc[ct], 0, 0, 0);
  }
  float sv[4];
#pragma unroll
  for (int r = 0; r < 4; ++r)
    sv[r] = scale ? scale[rowbase + quad * 4 + r] : 1.0f;
#pragma unroll
  for (int ct = 0; ct < 8; ++ct) {
    int colc = ct * 16 + m;
#pragma unroll
    for (int r = 0; r < 4; ++r)
      O[(size_t)(rowbase + quad * 4 + r) * F_ + colc] = (f16)(acc[ct][r] * sv[r]);
  }
}

// ---------------- aggregation (round-8 form): plain sums, 3-deep value pipeline ----------------
// s = Σ G'[src] + G'[row];  out = relu(ds·s + b) [· ds if SCALE_OUT]
template <int SCALE_OUT>
__global__ __launch_bounds__(256) void agg_kernel(const f16* __restrict__ X, f16* __restrict__ O,
                                                  const int* __restrict__ rp,
                                                  const int* __restrict__ rec,
                                                  const float* __restrict__ dinv,
                                                  const float* __restrict__ bias) {
  int wave = threadIdx.x >> 6, lane = threadIdx.x & 63;
  int eg = lane >> 4;
  int cb = (lane & 15) * 8;
  int b = blockIdx.x;
  int t = b & 7, i = b >> 3;                    // t-swizzled: per-XCD L2 locality on G slice
  int n = i * 4 + wave;
  int row = t * N_ + n;
  float ds = dinv[row];
  int beg = rp[t * (N_ + 1) + n], end = rp[t * (N_ + 1) + n + 1];
  beg = __builtin_amdgcn_readfirstlane(beg);
  end = __builtin_amdgcn_readfirstlane(end);
  const int* rcb = rec + (size_t)t * E_ + beg + eg;
  const f16* Xt = X + (size_t)t * N_ * F_;

  float s[8] = {0.f, 0.f, 0.f, 0.f, 0.f, 0.f, 0.f, 0.f};
  if (eg == 3) {                                // self-loop term on slot 3
    f16x8 v = *(const f16x8*)(Xt + (size_t)n * F_ + cb);
#pragma unroll
    for (int j = 0; j < 8; ++j) s[j] += (float)v[j];
  }
  int cnt = end - beg;
  int nq = cnt >> 2;
  if (nq > 0) {
    // 4 indices prefetched, 3 value loads in flight
    int rid0 = rcb[0];
    int rid1 = (nq > 1) ? rcb[4] : 0;
    int rid2 = (nq > 2) ? rcb[8] : 0;
    f16x8 vA = *(const f16x8*)(Xt + (size_t)rid0 * F_ + cb);
    f16x8 vB, vC;
    if (nq > 1) vB = *(const f16x8*)(Xt + (size_t)rid1 * F_ + cb);
    if (nq > 2) vC = *(const f16x8*)(Xt + (size_t)rid2 * F_ + cb);
    int ridN = (nq > 3) ? rcb[12] : 0;
    for (int q = 0; q + 3 < nq; ++q) {
      f16x8 vD = *(const f16x8*)(Xt + (size_t)ridN * F_ + cb);
      int ridNN = rcb[(q + 4) * 4];             // ≤3 ints past segment: lands in ws, unused unless valid
#pragma unroll
      for (int j = 0; j < 8; ++j) s[j] += (float)vA[j];
      vA = vB; vB = vC; vC = vD; ridN = ridNN;
    }
#pragma unroll
    for (int j = 0; j < 8; ++j) s[j] += (float)vA[j];
    if (nq > 1) {
#pragma unroll
      for (int j = 0; j < 8; ++j) s[j] += (float)vB[j];
    }
    if (nq > 2) {
#pragma unroll
      for (int j = 0; j < 8; ++j) s[j] += (float)vC[j];
    }
  }
  int rem = cnt & 3;
  if (eg < rem) {                               // tail: slots 0..rem-1
    int rid = rcb[nq * 4];
    f16x8 v = *(const f16x8*)(Xt + (size_t)rid * F_ + cb);
#pragma unroll
    for (int j = 0; j < 8; ++j) s[j] += (float)v[j];
  }
#pragma unroll
  for (int j = 0; j < 8; ++j) {                 // reduce the 4 edge slots
    s[j] += __shfl_xor(s[j], 16);
    s[j] += __shfl_xor(s[j], 32);
  }
  if (eg == 0) {
    float4 b0 = *(const float4*)(bias + cb);
    float4 b1v = *(const float4*)(bias + cb + 4);
    float bb[8] = {b0.x, b0.y, b0.z, b0.w, b1v.x, b1v.y, b1v.z, b1v.w};
    f16x8 o;
#pragma unroll
    for (int j = 0; j < 8; ++j) {
      float v = fmaxf(ds * s[j] + bb[j], 0.0f);
      if (SCALE_OUT) v *= ds;
      o[j] = (f16)v;
    }
    *(f16x8*)(O + (size_t)row * F_ + cb) = o;
  }
}

// ---------------- pool stage 1: one wave per (group, 1/8 slice) -> fp32 partials ----------------
__global__ void pool1_kernel(const f16* __restrict__ H, const int* __restrict__ brp,
                             const int* __restrict__ blist, float* __restrict__ part) {
  int b = blockIdx.x;                           // 512
  int wave = threadIdx.x >> 6, lane = threadIdx.x & 63;
  int idx = b >> 1;                             // t*G+g
  int s = (b & 1) * 4 + wave;                   // 0..7
  int beg = brp[idx], end = brp[idx + 1];
  beg = __builtin_amdgcn_readfirstlane(beg);
  end = __builtin_amdgcn_readfirstlane(end);
  int len = end - beg;
  int lo = beg + (int)(((long long)len * s) >> 3);
  int hi = beg + (int)(((long long)len * (s + 1)) >> 3);
  float a00 = 0.f, a01 = 0.f, a10 = 0.f, a11 = 0.f;
  float a20 = 0.f, a21 = 0.f, a30 = 0.f, a31 = 0.f;
  int e = lo;
  for (; e + 3 < hi; e += 4) {
    int r0 = blist[e], r1 = blist[e + 1], r2 = blist[e + 2], r3 = blist[e + 3];
    f16x2 v0 = *(const f16x2*)(H + (size_t)r0 * F_ + 2 * lane);
    f16x2 v1 = *(const f16x2*)(H + (size_t)r1 * F_ + 2 * lane);
    f16x2 v2 = *(const f16x2*)(H + (size_t)r2 * F_ + 2 * lane);
    f16x2 v3 = *(const f16x2*)(H + (size_t)r3 * F_ + 2 * lane);
    a00 += (float)v0.x; a01 += (float)v0.y;
    a10 += (float)v1.x; a11 += (float)v1.y;
    a20 += (float)v2.x; a21 += (float)v2.y;
    a30 += (float)v3.x; a31 += (float)v3.y;
  }
  for (; e < hi; ++e) {
    int r = blist[e];
    f16x2 v = *(const f16x2*)(H + (size_t)r * F_ + 2 * lane);
    a00 += (float)v.x; a01 += (float)v.y;
  }
  float2 o;
  o.x = (a00 + a10) + (a20 + a30);
  o.y = (a01 + a11) + (a21 + a31);
  *(float2*)(part + ((size_t)idx * 8 + s) * F_ + 2 * lane) = o;
}

// ---------------- mega tail: pool2 + gi0 + 2-layer GRU + final linear (16 blocks) ----------------
__global__ __launch_bounds__(256, 1) void gru_mega(
    const f16* __restrict__ gp, const float* __restrict__ part,
    const int* __restrict__ brp,
    const float* __restrict__ bih0, const float* __restrict__ bhh0,
    const float* __restrict__ bih1, const float* __restrict__ bhh1,
    const float* __restrict__ Wc, const float* __restrict__ bc,
    float* __restrict__ out) {
  __shared__ f16 emb_l[16][136];                // rows r = t*2+g2 for this block's 2 groups
  __shared__ float gib0[16][384];               // gi0 for all 8 t, 2 groups
  __shared__ f16 hb0[16 * 136];
  __shared__ f16 hb1[16 * 136];
  __shared__ float ghb[2 * 384];
  __shared__ float gib[2 * 384];
  __shared__ float h1s[2 * 128];
  int tid = threadIdx.x, wave = tid >> 6, lane = tid & 63;
  int quad = lane >> 4, mm = lane & 15;
  int g2 = tid >> 7, f = tid & 127;
  int bid = blockIdx.x;

  // ---- stage A: reduce pool partials -> mean -> f16 emb ----
  {
    int r = tid >> 4;                           // 0..15 = t*2+g2
    int fb = (tid & 15) * 8;
    int idx = (r >> 1) * G_ + bid * 2 + (r & 1);
    float s[8] = {0.f, 0.f, 0.f, 0.f, 0.f, 0.f, 0.f, 0.f};
#pragma unroll
    for (int k = 0; k < 8; ++k) {
      const float* p = part + ((size_t)idx * 8 + k) * F_ + fb;
      float4 v0 = *(const float4*)p;
      float4 v1 = *(const float4*)(p + 4);
      s[0] += v0.x; s[1] += v0.y; s[2] += v0.z; s[3] += v0.w;
      s[4] += v1.x; s[5] += v1.y; s[6] += v1.z; s[7] += v1.w;
    }
    float d = fmaxf((float)(brp[idx + 1] - brp[idx]), 1.0f);
    f16x8 ev;
#pragma unroll
    for (int j = 0; j < 8; ++j) ev[j] = (f16)(s[j] / d);
    *(f16x8*)(&emb_l[r][fb]) = ev;
  }
  __syncthreads();

  // ---- stage B: gi0 = emb @ Wih0^T, 16 rows x 384 cols, into LDS ----
  {
    floatx4 acc[6];
#pragma unroll
    for (int i = 0; i < 6; ++i) { floatx4 z = {0.f, 0.f, 0.f, 0.f}; acc[i] = z; }
#pragma unroll
    for (int kc = 0; kc < 4; ++kc) {
      f16x8 a = *(const f16x8*)(&emb_l[mm][kc * 32 + quad * 8]);
#pragma unroll
      for (int i = 0; i < 6; ++i) {
        int nt = wave * 6 + i;
        f16x8 bf = *(const f16x8*)(gp + (size_t)((nt * 4 + kc) * 64 + lane) * 8);
        acc[i] = __builtin_amdgcn_mfma_f32_16x16x32_f16(a, bf, acc[i], 0, 0, 0);
      }
    }
#pragma unroll
    for (int i = 0; i < 6; ++i)
#pragma unroll
      for (int r = 0; r < 4; ++r)
        gib0[quad * 4 + r][(wave * 6 + i) * 16 + mm] = acc[i][r];
  }

  // ---- persistent recurrent weight fragments ----
  f16x8 B0[24], B1[24];
#pragma unroll
  for (int i = 0; i < 6; ++i)
#pragma unroll
    for (int kc = 0; kc < 4; ++kc) {
      size_t off = (size_t)((((wave * 6 + i) * 4 + kc) * 64 + lane)) * 8;
      B0[i * 4 + kc] = *(const f16x8*)(gp + 1 * 49152 + off);
      B1[i * 4 + kc] = *(const f16x8*)(gp + 3 * 49152 + off);
    }
  float br0 = bih0[f] + bhh0[f];
  float bz0 = bih0[128 + f] + bhh0[128 + f];
  float bni0 = bih0[256 + f], bnh0 = bhh0[256 + f];
  float br1 = bih1[f] + bhh1[f];
  float bz1 = bih1[128 + f] + bhh1[128 + f];
  float bni1 = bih1[256 + f], bnh1 = bhh1[256 + f];

  for (int i = tid; i < 16 * 136; i += 256) { hb0[i] = (f16)0.f; hb1[i] = (f16)0.f; }
  float h0 = 0.f, h1 = 0.f;
  __syncthreads();                              // covers gib0 writes + hb inits

  const f16* wih1 = gp + 2 * 49152;
  for (int t = 0; t < T_; ++t) {
    f16x8 Bs[24];
#pragma unroll
    for (int i = 0; i < 6; ++i)
#pragma unroll
      for (int kc = 0; kc < 4; ++kc)
        Bs[i * 4 + kc] = *(const f16x8*)(wih1 +
            (size_t)((((wave * 6 + i) * 4 + kc) * 64 + lane)) * 8);
    const float* gi = &gib0[t * 2 + g2][0];
    float gir = gi[f], giz = gi[128 + f], gin = gi[256 + f];

    floatx4 acc[6];
#pragma unroll
    for (int i = 0; i < 6; ++i) { floatx4 z = {0.f, 0.f, 0.f, 0.f}; acc[i] = z; }
#pragma unroll
    for (int kc = 0; kc < 4; ++kc) {
      f16x8 a = *(const f16x8*)(hb0 + mm * 136 + kc * 32 + quad * 8);
#pragma unroll
      for (int i = 0; i < 6; ++i)
        acc[i] = __builtin_amdgcn_mfma_f32_16x16x32_f16(a, B0[i * 4 + kc], acc[i], 0, 0, 0);
    }
    if (quad == 0) {
#pragma unroll
      for (int i = 0; i < 6; ++i) {
        ghb[0 * 384 + wave * 96 + i * 16 + mm] = acc[i][0];
        ghb[1 * 384 + wave * 96 + i * 16 + mm] = acc[i][1];
      }
    }
    __syncthreads();

    {
      float hr = ghb[g2 * 384 + f];
      float hz = ghb[g2 * 384 + 128 + f];
      float hn = ghb[g2 * 384 + 256 + f];
      float r = sig_fast(gir + hr + br0);
      float z = sig_fast(giz + hz + bz0);
      float nn = tanh_fast(gin + bni0 + r * (hn + bnh0));
      h0 = (1.0f - z) * nn + z * h0;
      hb0[g2 * 136 + f] = (f16)h0;
    }
    __syncthreads();

    floatx4 accx[6], acch[6];
#pragma unroll
    for (int i = 0; i < 6; ++i) {
      floatx4 z = {0.f, 0.f, 0.f, 0.f}; accx[i] = z; acch[i] = z;
    }
#pragma unroll
    for (int kc = 0; kc < 4; ++kc) {
      f16x8 ax = *(const f16x8*)(hb0 + mm * 136 + kc * 32 + quad * 8);
      f16x8 ah = *(const f16x8*)(hb1 + mm * 136 + kc * 32 + quad * 8);
#pragma unroll
      for (int i = 0; i < 6; ++i) {
        accx[i] = __builtin_amdgcn_mfma_f32_16x16x32_f16(ax, Bs[i * 4 + kc], accx[i], 0, 0, 0);
        acch[i] = __builtin_amdgcn_mfma_f32_16x16x32_f16(ah, B1[i * 4 + kc], acch[i], 0, 0, 0);
      }
    }
    if (quad == 0) {
#pragma unroll
      for (int i = 0; i < 6; ++i) {
        gib[0 * 384 + wave * 96 + i * 16 + mm] = accx[i][0];
        gib[1 * 384 + wave * 96 + i * 16 + mm] = accx[i][1];
        ghb[0 * 384 + wave * 96 + i * 16 + mm] = acch[i][0];
        ghb[1 * 384 + wave * 96 + i * 16 + mm] = acch[i][1];
      }
    }
    __syncthreads();

    {
      float i1r = gib[g2 * 384 + f];
      float i1z = gib[g2 * 384 + 128 + f];
      float i1n = gib[g2 * 384 + 256 + f];
      float hr = ghb[g2 * 384 + f];
      float hz = ghb[g2 * 384 + 128 + f];
      float hn = ghb[g2 * 384 + 256 + f];
      float r = sig_fast(i1r + hr + br1);
      float z = sig_fast(i1z + hz + bz1);
      float nn = tanh_fast(i1n + bni1 + r * (hn + bnh1));
      h1 = (1.0f - z) * nn + z * h1;
      hb1[g2 * 136 + f] = (f16)h1;
    }
    __syncthreads();
  }

  h1s[g2 * 128 + f] = h1;
  __syncthreads();
  if (tid < 2 * C_) {
    int gg = tid / C_, c = tid - gg * C_;
    float s = bc[c];
    const float* wr = Wc + (size_t)c * 128;
    const float* hr = h1s + gg * 128;
    for (int k = 0; k < 128; k += 4) {
      float4 w = *(const float4*)(wr + k);
      s += hr[k] * w.x + hr[k + 1] * w.y + hr[k + 2] * w.z + hr[k + 3] * w.w;
    }
    out[(bid * 2 + gg) * C_ + c] = s;
  }
}

extern "C" void kernel_launch(void* const* d_in, const int* in_sizes, int n_in,
                              void* d_out, int out_size, void* d_ws, size_t ws_size,
                              hipStream_t stream) {
  const float* x    = (const float*)d_in[0];
  const int*   ei   = (const int*)d_in[1];
  const int*   batch= (const int*)d_in[2];
  const float* W1   = (const float*)d_in[3];
  const float* b1   = (const float*)d_in[4];
  const float* W2   = (const float*)d_in[5];
  const float* b2   = (const float*)d_in[6];
  const float* Wih0 = (const float*)d_in[7];
  const float* Whh0 = (const float*)d_in[8];
  const float* bih0 = (const float*)d_in[9];
  const float* bhh0 = (const float*)d_in[10];
  const float* Wih1 = (const float*)d_in[11];
  const float* Whh1 = (const float*)d_in[12];
  const float* bih1 = (const float*)d_in[13];
  const float* bhh1 = (const float*)d_in[14];
  const float* Wc   = (const float*)d_in[15];
  const float* bc   = (const float*)d_in[16];
  float* out = (float*)d_out;

  char* ws = (char*)d_ws;
  f16*   H2    = (f16*)(ws + OFF_H2);
  f16*   G     = (f16*)(ws + OFF_G);   // G1' = dinv*(x*W1); reused as G2 = H1'*W2
  f16*   H1p   = (f16*)(ws + OFF_H1);
  int*   rec   = (int*)(ws + OFF_REC);
  int*   cnt   = (int*)(ws + OFF_CNT);
  float* dinv  = (float*)(ws + OFF_DINV);
  int*   rp    = (int*)(ws + OFF_RP);
  int*   cntG  = (int*)(ws + OFF_CNTG);
  int*   brp   = (int*)(ws + OFF_BRP);
  f16*   Wp    = (f16*)(ws + OFF_WP);
  int*   blist = (int*)(ws + OFF_BLIST);
  f16*   gp    = (f16*)(ws + OFF_GPACK);
  float* part  = (float*)(ws + OFF_PART);

  prep0_kernel<<<352, 1024, 0, stream>>>(ei, batch, cnt, cntG,
                                         W1, W2, Wp, Wih0, Whh0, Wih1, Whh1, gp);
  scan_kernel<<<9, 1024, 0, stream>>>(cnt, rp, dinv, cntG, brp);
  // G1' = dinv * (x*W1): fp32 read, in-register cvt, dinv row-scale epilogue
  gemm_kernel<1><<<1250, 256, 0, stream>>>(x, Wp, G, dinv);
  fill_kernel<<<128, 1024, 0, stream>>>(ei, cnt, rec, batch, brp, blist);

  agg_kernel<1><<<20000, 256, 0, stream>>>(G, H1p, rp, rec, dinv, b1);
  gemm_kernel<0><<<1250, 256, 0, stream>>>(H1p, Wp + 16384, G, nullptr);
  agg_kernel<0><<<20000, 256, 0, stream>>>(G, H2, rp, rec, dinv, b2);

  pool1_kernel<<<512, 256, 0, stream>>>(H2, brp, blist, part);
  gru_mega<<<16, 256, 0, stream>>>(gp, part, brp, bih0, bhh0, bih1, bhh1, Wc, bc, out);
}

// Round 11
// 288.705 us; speedup vs baseline: 1.0221x; 1.0216x over previous
//
#include <hip/hip_runtime.h>

#define T_ 8
#define N_ 10000
#define E_ 160000
#define G_ 32
#define C_ 10
#define F_ 128

typedef _Float16 f16;
typedef _Float16 f16x2 __attribute__((ext_vector_type(2)));
typedef _Float16 f16x4 __attribute__((ext_vector_type(4)));
typedef _Float16 f16x8 __attribute__((ext_vector_type(8)));
typedef float floatx4 __attribute__((ext_vector_type(4)));

static constexpr int NSL = 16;                    // preproc slices per t
static constexpr int SLICE = E_ / NSL;            // 10000 edges per (t, slice)

// ---------------- workspace layout (bytes) ----------------
static constexpr size_t OFF_H2    = 0;          // f16 [80000][128] layer-2 output (pool input)
static constexpr size_t OFF_G     = 20480000;   // f16 [80000][128] G1' = dinv*(x*W1), reused as G2 = H1'*W2
static constexpr size_t OFF_H1    = 40960000;   // f16 [80000][128] H1' = dinv*relu(layer1)
static constexpr size_t OFF_REC   = 61440000;   // int [T][E] src, grouped by dst
static constexpr size_t OFF_CNT   = 66560000;   // int [T][16][N] slice hist -> slice base (5.12 MB)
static constexpr size_t OFF_DINV  = 71680000;   // float [T][N]
static constexpr size_t OFF_RP    = 72000000;   // int [T][N+1]
static constexpr size_t OFF_CNTG  = 72320032;   // int [T*G]
static constexpr size_t OFF_BRP   = 72321056;   // int [T*G+1]
static constexpr size_t OFF_WP    = 72322112;   // f16 packed W1,W2 (2*16384), 16B-aligned
static constexpr size_t OFF_BLIST = 72387648;   // int [80000]
static constexpr size_t OFF_GPACK = 72707648;   // f16 4*49152 packed GRU weights
static constexpr size_t OFF_PART  = 73100864;   // float [256][8][128] pool partials
// end ~74.2 MB

// ---------------- fast gates (v_exp_f32 / v_rcp_f32, ~1 ulp) ----------------
__device__ __forceinline__ float sig_fast(float x) {
  return __builtin_amdgcn_rcpf(1.0f + __builtin_amdgcn_exp2f(-1.4426950408889634f * x));
}
__device__ __forceinline__ float tanh_fast(float x) {
  return 1.0f - 2.0f * __builtin_amdgcn_rcpf(1.0f + __builtin_amdgcn_exp2f(2.8853900817779268f * x));
}

// ---------------- fused phase 1: blocks 0..127 = hist (t,s), blocks 128..351 = weight pack ----------------
__global__ __launch_bounds__(1024) void prep0_kernel(const int* __restrict__ ei,
                                                     const int* __restrict__ batch,
                                                     int* __restrict__ cnt,
                                                     int* __restrict__ cntG,
                                                     const float* __restrict__ W1,
                                                     const float* __restrict__ W2,
                                                     f16* __restrict__ Wp,
                                                     const float* __restrict__ A0,
                                                     const float* __restrict__ A1,
                                                     const float* __restrict__ A2,
                                                     const float* __restrict__ A3,
                                                     f16* __restrict__ gp) {
  __shared__ int hL[N_];                        // 40 KB (hist blocks only)
  __shared__ int cL[G_];
  int b = blockIdx.x, tid = threadIdx.x;
  if (b >= 128) {
    // ---- pack role ----
    int idx = (b - 128) * 1024 + tid;           // < 224*1024 = 229376
    if (idx < 32768) {
      const float* W = (idx < 16384) ? W1 : W2;
      int l = idx & 16383;
      int j = l & 7, lane = (l >> 3) & 63, ct = (l >> 9) & 7, kc = (l >> 12) & 3;
      int k = kc * 32 + ((lane >> 4) & 3) * 8 + j;
      int n = ct * 16 + (lane & 15);
      Wp[idx] = (f16)W[k * 128 + n];
    } else {
      int gidx = idx - 32768;                   // < 196608
      int mat = gidx / 49152, l = gidx - mat * 49152;
      int j = l & 7, lane = (l >> 3) & 63, kc = (l >> 9) & 3, nt = l >> 11;
      int k = kc * 32 + ((lane >> 4) & 3) * 8 + j;
      int u = nt * 16 + (lane & 15);
      const float* W = (mat == 0) ? A0 : (mat == 1) ? A1 : (mat == 2) ? A2 : A3;
      gp[gidx] = (f16)W[u * 128 + k];
    }
    return;
  }
  // ---- hist role: one (t, s) slice per block ----
  int t = b & 7, s = b >> 3;                    // XCD-swizzled by t; s in 0..15
  for (int i = tid; i < N_; i += 1024) hL[i] = 0;
  if (tid < G_) cL[tid] = 0;
  __syncthreads();
  const int* dstp = ei + (size_t)t * 2 * E_ + E_ + s * SLICE;
  for (int e4 = tid; e4 < SLICE / 4; e4 += 1024) {
    int4 d = *(const int4*)(dstp + e4 * 4);
    atomicAdd(&hL[d.x], 1); atomicAdd(&hL[d.y], 1);
    atomicAdd(&hL[d.z], 1); atomicAdd(&hL[d.w], 1);
  }
  if (s == 0)
    for (int n = tid; n < N_; n += 1024) atomicAdd(&cL[batch[t * N_ + n]], 1);
  __syncthreads();
  int* cp = cnt + ((size_t)t * NSL + s) * N_;
  for (int i = tid; i < N_; i += 1024) cp[i] = hL[i];
  if (s == 0 && tid < G_) cntG[t * G_ + tid] = cL[tid];
}

// ---------------- phase 2: per-t scan -> rp, dinv, in-place slice bases; blk8 -> brp ----------------
__global__ __launch_bounds__(1024) void scan_kernel(int* __restrict__ cnt,
                                                    int* __restrict__ rp,
                                                    float* __restrict__ dinv,
                                                    const int* __restrict__ cntG,
                                                    int* __restrict__ brp) {
  __shared__ int wsum[16];
  __shared__ int carry;
  int t = blockIdx.x, tid = threadIdx.x, lane = tid & 63, wid = tid >> 6;
  if (t == 8) {
    int v = (tid < 256) ? cntG[tid] : 0;
    for (int ofs = 1; ofs < 64; ofs <<= 1) {
      int u = __shfl_up(v, ofs);
      if (lane >= ofs) v += u;
    }
    if (lane == 63 && wid < 4) wsum[wid] = v;
    __syncthreads();
    if (tid < 256) {
      int base = 0;
      for (int w = 0; w < wid; ++w) base += wsum[w];
      if (tid == 0) brp[0] = 0;
      brp[tid + 1] = v + base;
    }
    return;
  }
  if (tid == 0) { carry = 0; rp[t * (N_ + 1)] = 0; }
  __syncthreads();
  for (int c0 = 0; c0 < N_; c0 += 1024) {
    int n = c0 + tid;
    int vs[NSL];
    int deg = 0;
    if (n < N_) {
#pragma unroll
      for (int s = 0; s < NSL; ++s) {
        vs[s] = cnt[((size_t)t * NSL + s) * N_ + n];
        deg += vs[s];
      }
      dinv[t * N_ + n] = rsqrtf((float)deg + 1.0f);
    }
    int v = (n < N_) ? deg : 0;
    int v0 = v;
    for (int ofs = 1; ofs < 64; ofs <<= 1) {
      int u = __shfl_up(v, ofs);
      if (lane >= ofs) v += u;
    }
    if (lane == 63) wsum[wid] = v;
    __syncthreads();
    if (wid == 0) {
      int w = (lane < 16) ? wsum[lane] : 0;
      for (int ofs = 1; ofs < 16; ofs <<= 1) {
        int u = __shfl_up(w, ofs);
        if (lane >= ofs) w += u;
      }
      if (lane < 16) wsum[lane] = w;
    }
    __syncthreads();
    int base = carry + (wid ? wsum[wid - 1] : 0);
    if (n < N_) {
      rp[t * (N_ + 1) + n + 1] = base + v;
      int run = base + v - v0;
#pragma unroll
      for (int s = 0; s < NSL; ++s) {
        int vv = vs[s];
        cnt[((size_t)t * NSL + s) * N_ + n] = run;
        run += vv;
      }
    }
    __syncthreads();
    if (tid == 0) carry += wsum[15];
    __syncthreads();
  }
}

// ---------------- fused phase 3: blocks 0..312 = G1'=dinv*(x@W1) (4x64-row tiles),
//                  blocks 313..440 = CSR fill + blist ----------------
__global__ __launch_bounds__(1024) void gxfill_kernel(const float* __restrict__ x,
                                                      const f16* __restrict__ Wp,
                                                      f16* __restrict__ Gout,
                                                      const float* __restrict__ dinv,
                                                      const int* __restrict__ ei,
                                                      const int* __restrict__ base,
                                                      int* __restrict__ rec,
                                                      const int* __restrict__ batch,
                                                      const int* __restrict__ brp,
                                                      int* __restrict__ blist) {
  __shared__ union {
    f16x8 Bp[2048];                             // 32 KB (gemm role)
    struct { int offL[N_]; int cb[G_]; } fl;    // 40.1 KB (fill role)
  } U;
  int b = blockIdx.x, tid = threadIdx.x;
  if (b < 313) {
    // ---- gemm role: rows b*256 + sub*64, sub = tid>>8 ----
    const f16x8* Wv = (const f16x8*)Wp;
    for (int i = tid; i < 2048; i += 1024) U.Bp[i] = Wv[i];
    __syncthreads();
    int stid = tid & 255;
    int sub = tid >> 8;
    int wave = stid >> 6, lane = stid & 63;
    int quad = lane >> 4, m = lane & 15;
    int rowbase = b * 256 + sub * 64 + wave * 16;
    if (rowbase >= 80000) return;
    floatx4 acc[8];
#pragma unroll
    for (int ct = 0; ct < 8; ++ct) { floatx4 z = {0.f, 0.f, 0.f, 0.f}; acc[ct] = z; }
#pragma unroll
    for (int kc = 0; kc < 4; ++kc) {
      const float* Ar = x + (size_t)(rowbase + m) * F_ + kc * 32 + quad * 8;
      float4 lo = *(const float4*)Ar;
      float4 hi = *(const float4*)(Ar + 4);
      f16x8 a;
      a[0] = (f16)lo.x; a[1] = (f16)lo.y; a[2] = (f16)lo.z; a[3] = (f16)lo.w;
      a[4] = (f16)hi.x; a[5] = (f16)hi.y; a[6] = (f16)hi.z; a[7] = (f16)hi.w;
#pragma unroll
      for (int ct = 0; ct < 8; ++ct)
        acc[ct] = __builtin_amdgcn_mfma_f32_16x16x32_f16(a, U.Bp[(kc * 8 + ct) * 64 + lane],
                                                         acc[ct], 0, 0, 0);
    }
    float sv[4];
#pragma unroll
    for (int r = 0; r < 4; ++r) sv[r] = dinv[rowbase + quad * 4 + r];
#pragma unroll
    for (int ct = 0; ct < 8; ++ct) {
      int colc = ct * 16 + m;
#pragma unroll
      for (int r = 0; r < 4; ++r)
        Gout[(size_t)(rowbase + quad * 4 + r) * F_ + colc] = (f16)(acc[ct][r] * sv[r]);
    }
    return;
  }
  // ---- fill role: one (t, s) slice per block ----
  int b2 = b - 313;
  int t = b2 & 7, s = b2 >> 3;
  const int* bp = base + ((size_t)t * NSL + s) * N_;
  for (int i = tid; i < N_; i += 1024) U.fl.offL[i] = bp[i];
  if (s == 0 && tid < G_) U.fl.cb[tid] = brp[t * G_ + tid];
  __syncthreads();
  const int* srcp = ei + (size_t)t * 2 * E_ + s * SLICE;
  const int* dstp = srcp + E_;
  int* rt = rec + (size_t)t * E_;
  for (int e4 = tid; e4 < SLICE / 4; e4 += 1024) {
    int4 sv = *(const int4*)(srcp + e4 * 4);
    int4 dv = *(const int4*)(dstp + e4 * 4);
    int p0 = atomicAdd(&U.fl.offL[dv.x], 1);
    int p1 = atomicAdd(&U.fl.offL[dv.y], 1);
    int p2 = atomicAdd(&U.fl.offL[dv.z], 1);
    int p3 = atomicAdd(&U.fl.offL[dv.w], 1);
    rt[p0] = sv.x; rt[p1] = sv.y; rt[p2] = sv.z; rt[p3] = sv.w;
  }
  if (s == 0) {
    for (int n = tid; n < N_; n += 1024) {
      int g = batch[t * N_ + n];
      int p = atomicAdd(&U.fl.cb[g], 1);
      blist[p] = t * N_ + n;
    }
  }
}

// ---------------- GEMM (f16 A): O = A @ W, MFMA 16x16x32 ----------------
__global__ __launch_bounds__(256) void gemm_kernel(const f16* __restrict__ A,
                                                   const f16* __restrict__ Wp,
                                                   f16* __restrict__ O) {
  __shared__ f16x8 Bp[2048];                    // 32 KB packed W
  const f16x8* Wv = (const f16x8*)Wp;
  for (int i = threadIdx.x; i < 2048; i += 256) Bp[i] = Wv[i];
  __syncthreads();
  int wave = threadIdx.x >> 6, lane = threadIdx.x & 63;
  int quad = lane >> 4, m = lane & 15;
  int rowbase = blockIdx.x * 64 + wave * 16;
  const f16x8* Arow = (const f16x8*)(A + (size_t)(rowbase + m) * F_);
  floatx4 acc[8];
#pragma unroll
  for (int ct = 0; ct < 8; ++ct) { floatx4 z = {0.f, 0.f, 0.f, 0.f}; acc[ct] = z; }
#pragma unroll
  for (int kc = 0; kc < 4; ++kc) {
    f16x8 a = Arow[kc * 4 + quad];
#pragma unroll
    for (int ct = 0; ct < 8; ++ct)
      acc[ct] = __builtin_amdgcn_mfma_f32_16x16x32_f16(a, Bp[(kc * 8 + ct) * 64 + lane],
                                                       acc[ct], 0, 0, 0);
  }
#pragma unroll
  for (int ct = 0; ct < 8; ++ct) {
    int colc = ct * 16 + m;
#pragma unroll
    for (int r = 0; r < 4; ++r)
      O[(size_t)(rowbase + quad * 4 + r) * F_ + colc] = (f16)acc[ct][r];
  }
}

// ---------------- aggregation: plain sums, 3-deep value pipeline ----------------
// s = Σ G'[src] + G'[row];  out = relu(ds·s + b) [· ds if SCALE_OUT]
template <int SCALE_OUT>
__global__ __launch_bounds__(256) void agg_kernel(const f16* __restrict__ X, f16* __restrict__ O,
                                                  const int* __restrict__ rp,
                                                  const int* __restrict__ rec,
                                                  const float* __restrict__ dinv,
                                                  const float* __restrict__ bias) {
  int wave = threadIdx.x >> 6, lane = threadIdx.x & 63;
  int eg = lane >> 4;
  int cb = (lane & 15) * 8;
  int b = blockIdx.x;
  int t = b & 7, i = b >> 3;                    // t-swizzled: per-XCD L2 locality on G slice
  int n = i * 4 + wave;
  int row = t * N_ + n;
  float ds = dinv[row];
  int beg = rp[t * (N_ + 1) + n], end = rp[t * (N_ + 1) + n + 1];
  beg = __builtin_amdgcn_readfirstlane(beg);
  end = __builtin_amdgcn_readfirstlane(end);
  const int* rcb = rec + (size_t)t * E_ + beg + eg;
  const f16* Xt = X + (size_t)t * N_ * F_;

  float s[8] = {0.f, 0.f, 0.f, 0.f, 0.f, 0.f, 0.f, 0.f};
  if (eg == 3) {                                // self-loop term on slot 3
    f16x8 v = *(const f16x8*)(Xt + (size_t)n * F_ + cb);
#pragma unroll
    for (int j = 0; j < 8; ++j) s[j] += (float)v[j];
  }
  int cnt = end - beg;
  int nq = cnt >> 2;
  if (nq > 0) {
    // 4 indices prefetched, 3 value loads in flight
    int rid0 = rcb[0];
    int rid1 = (nq > 1) ? rcb[4] : 0;
    int rid2 = (nq > 2) ? rcb[8] : 0;
    f16x8 vA = *(const f16x8*)(Xt + (size_t)rid0 * F_ + cb);
    f16x8 vB, vC;
    if (nq > 1) vB = *(const f16x8*)(Xt + (size_t)rid1 * F_ + cb);
    if (nq > 2) vC = *(const f16x8*)(Xt + (size_t)rid2 * F_ + cb);
    int ridN = (nq > 3) ? rcb[12] : 0;
    for (int q = 0; q + 3 < nq; ++q) {
      f16x8 vD = *(const f16x8*)(Xt + (size_t)ridN * F_ + cb);
      int ridNN = rcb[(q + 4) * 4];             // ≤3 ints past segment: lands in ws, unused unless valid
#pragma unroll
      for (int j = 0; j < 8; ++j) s[j] += (float)vA[j];
      vA = vB; vB = vC; vC = vD; ridN = ridNN;
    }
#pragma unroll
    for (int j = 0; j < 8; ++j) s[j] += (float)vA[j];
    if (nq > 1) {
#pragma unroll
      for (int j = 0; j < 8; ++j) s[j] += (float)vB[j];
    }
    if (nq > 2) {
#pragma unroll
      for (int j = 0; j < 8; ++j) s[j] += (float)vC[j];
    }
  }
  int rem = cnt & 3;
  if (eg < rem) {                               // tail: slots 0..rem-1
    int rid = rcb[nq * 4];
    f16x8 v = *(const f16x8*)(Xt + (size_t)rid * F_ + cb);
#pragma unroll
    for (int j = 0; j < 8; ++j) s[j] += (float)v[j];
  }
#pragma unroll
  for (int j = 0; j < 8; ++j) {                 // reduce the 4 edge slots
    s[j] += __shfl_xor(s[j], 16);
    s[j] += __shfl_xor(s[j], 32);
  }
  if (eg == 0) {
    float4 b0 = *(const float4*)(bias + cb);
    float4 b1v = *(const float4*)(bias + cb + 4);
    float bb[8] = {b0.x, b0.y, b0.z, b0.w, b1v.x, b1v.y, b1v.z, b1v.w};
    f16x8 o;
#pragma unroll
    for (int j = 0; j < 8; ++j) {
      float v = fmaxf(ds * s[j] + bb[j], 0.0f);
      if (SCALE_OUT) v *= ds;
      o[j] = (f16)v;
    }
    *(f16x8*)(O + (size_t)row * F_ + cb) = o;
  }
}

// ---------------- pool stage 1: one wave per (group, 1/8 slice) -> fp32 partials ----------------
__global__ void pool1_kernel(const f16* __restrict__ H, const int* __restrict__ brp,
                             const int* __restrict__ blist, float* __restrict__ part) {
  int b = blockIdx.x;                           // 512
  int wave = threadIdx.x >> 6, lane = threadIdx.x & 63;
  int idx = b >> 1;                             // t*G+g
  int s = (b & 1) * 4 + wave;                   // 0..7
  int beg = brp[idx], end = brp[idx + 1];
  beg = __builtin_amdgcn_readfirstlane(beg);
  end = __builtin_amdgcn_readfirstlane(end);
  int len = end - beg;
  int lo = beg + (int)(((long long)len * s) >> 3);
  int hi = beg + (int)(((long long)len * (s + 1)) >> 3);
  float a00 = 0.f, a01 = 0.f, a10 = 0.f, a11 = 0.f;
  float a20 = 0.f, a21 = 0.f, a30 = 0.f, a31 = 0.f;
  int e = lo;
  for (; e + 3 < hi; e += 4) {
    int r0 = blist[e], r1 = blist[e + 1], r2 = blist[e + 2], r3 = blist[e + 3];
    f16x2 v0 = *(const f16x2*)(H + (size_t)r0 * F_ + 2 * lane);
    f16x2 v1 = *(const f16x2*)(H + (size_t)r1 * F_ + 2 * lane);
    f16x2 v2 = *(const f16x2*)(H + (size_t)r2 * F_ + 2 * lane);
    f16x2 v3 = *(const f16x2*)(H + (size_t)r3 * F_ + 2 * lane);
    a00 += (float)v0.x; a01 += (float)v0.y;
    a10 += (float)v1.x; a11 += (float)v1.y;
    a20 += (float)v2.x; a21 += (float)v2.y;
    a30 += (float)v3.x; a31 += (float)v3.y;
  }
  for (; e < hi; ++e) {
    int r = blist[e];
    f16x2 v = *(const f16x2*)(H + (size_t)r * F_ + 2 * lane);
    a00 += (float)v.x; a01 += (float)v.y;
  }
  float2 o;
  o.x = (a00 + a10) + (a20 + a30);
  o.y = (a01 + a11) + (a21 + a31);
  *(float2*)(part + ((size_t)idx * 8 + s) * F_ + 2 * lane) = o;
}

// ---------------- mega tail: pool2 + gi0 + 2-layer GRU + final linear (16 blocks) ----------------
__global__ __launch_bounds__(256, 1) void gru_mega(
    const f16* __restrict__ gp, const float* __restrict__ part,
    const int* __restrict__ brp,
    const float* __restrict__ bih0, const float* __restrict__ bhh0,
    const float* __restrict__ bih1, const float* __restrict__ bhh1,
    const float* __restrict__ Wc, const float* __restrict__ bc,
    float* __restrict__ out) {
  __shared__ f16 emb_l[16][136];                // rows r = t*2+g2 for this block's 2 groups
  __shared__ float gib0[16][384];               // gi0 for all 8 t, 2 groups
  __shared__ f16 hb0[16 * 136];
  __shared__ f16 hb1[16 * 136];
  __shared__ float ghb[2 * 384];
  __shared__ float gib[2 * 384];
  __shared__ float h1s[2 * 128];
  int tid = threadIdx.x, wave = tid >> 6, lane = tid & 63;
  int quad = lane >> 4, mm = lane & 15;
  int g2 = tid >> 7, f = tid & 127;
  int bid = blockIdx.x;

  // ---- stage A: reduce pool partials -> mean -> f16 emb ----
  {
    int r = tid >> 4;                           // 0..15 = t*2+g2
    int fb = (tid & 15) * 8;
    int idx = (r >> 1) * G_ + bid * 2 + (r & 1);
    float s[8] = {0.f, 0.f, 0.f, 0.f, 0.f, 0.f, 0.f, 0.f};
#pragma unroll
    for (int k = 0; k < 8; ++k) {
      const float* p = part + ((size_t)idx * 8 + k) * F_ + fb;
      float4 v0 = *(const float4*)p;
      float4 v1 = *(const float4*)(p + 4);
      s[0] += v0.x; s[1] += v0.y; s[2] += v0.z; s[3] += v0.w;
      s[4] += v1.x; s[5] += v1.y; s[6] += v1.z; s[7] += v1.w;
    }
    float d = fmaxf((float)(brp[idx + 1] - brp[idx]), 1.0f);
    f16x8 ev;
#pragma unroll
    for (int j = 0; j < 8; ++j) ev[j] = (f16)(s[j] / d);
    *(f16x8*)(&emb_l[r][fb]) = ev;
  }
  __syncthreads();

  // ---- stage B: gi0 = emb @ Wih0^T, 16 rows x 384 cols, into LDS ----
  {
    floatx4 acc[6];
#pragma unroll
    for (int i = 0; i < 6; ++i) { floatx4 z = {0.f, 0.f, 0.f, 0.f}; acc[i] = z; }
#pragma unroll
    for (int kc = 0; kc < 4; ++kc) {
      f16x8 a = *(const f16x8*)(&emb_l[mm][kc * 32 + quad * 8]);
#pragma unroll
      for (int i = 0; i < 6; ++i) {
        int nt = wave * 6 + i;
        f16x8 bf = *(const f16x8*)(gp + (size_t)((nt * 4 + kc) * 64 + lane) * 8);
        acc[i] = __builtin_amdgcn_mfma_f32_16x16x32_f16(a, bf, acc[i], 0, 0, 0);
      }
    }
#pragma unroll
    for (int i = 0; i < 6; ++i)
#pragma unroll
      for (int r = 0; r < 4; ++r)
        gib0[quad * 4 + r][(wave * 6 + i) * 16 + mm] = acc[i][r];
  }

  // ---- persistent recurrent weight fragments ----
  f16x8 B0[24], B1[24];
#pragma unroll
  for (int i = 0; i < 6; ++i)
#pragma unroll
    for (int kc = 0; kc < 4; ++kc) {
      size_t off = (size_t)((((wave * 6 + i) * 4 + kc) * 64 + lane)) * 8;
      B0[i * 4 + kc] = *(const f16x8*)(gp + 1 * 49152 + off);
      B1[i * 4 + kc] = *(const f16x8*)(gp + 3 * 49152 + off);
    }
  float br0 = bih0[f] + bhh0[f];
  float bz0 = bih0[128 + f] + bhh0[128 + f];
  float bni0 = bih0[256 + f], bnh0 = bhh0[256 + f];
  float br1 = bih1[f] + bhh1[f];
  float bz1 = bih1[128 + f] + bhh1[128 + f];
  float bni1 = bih1[256 + f], bnh1 = bhh1[256 + f];

  for (int i = tid; i < 16 * 136; i += 256) { hb0[i] = (f16)0.f; hb1[i] = (f16)0.f; }
  float h0 = 0.f, h1 = 0.f;
  __syncthreads();                              // covers gib0 writes + hb inits

  const f16* wih1 = gp + 2 * 49152;
  for (int t = 0; t < T_; ++t) {
    f16x8 Bs[24];
#pragma unroll
    for (int i = 0; i < 6; ++i)
#pragma unroll
      for (int kc = 0; kc < 4; ++kc)
        Bs[i * 4 + kc] = *(const f16x8*)(wih1 +
            (size_t)((((wave * 6 + i) * 4 + kc) * 64 + lane)) * 8);
    const float* gi = &gib0[t * 2 + g2][0];
    float gir = gi[f], giz = gi[128 + f], gin = gi[256 + f];

    floatx4 acc[6];
#pragma unroll
    for (int i = 0; i < 6; ++i) { floatx4 z = {0.f, 0.f, 0.f, 0.f}; acc[i] = z; }
#pragma unroll
    for (int kc = 0; kc < 4; ++kc) {
      f16x8 a = *(const f16x8*)(hb0 + mm * 136 + kc * 32 + quad * 8);
#pragma unroll
      for (int i = 0; i < 6; ++i)
        acc[i] = __builtin_amdgcn_mfma_f32_16x16x32_f16(a, B0[i * 4 + kc], acc[i], 0, 0, 0);
    }
    if (quad == 0) {
#pragma unroll
      for (int i = 0; i < 6; ++i) {
        ghb[0 * 384 + wave * 96 + i * 16 + mm] = acc[i][0];
        ghb[1 * 384 + wave * 96 + i * 16 + mm] = acc[i][1];
      }
    }
    __syncthreads();

    {
      float hr = ghb[g2 * 384 + f];
      float hz = ghb[g2 * 384 + 128 + f];
      float hn = ghb[g2 * 384 + 256 + f];
      float r = sig_fast(gir + hr + br0);
      float z = sig_fast(giz + hz + bz0);
      float nn = tanh_fast(gin + bni0 + r * (hn + bnh0));
      h0 = (1.0f - z) * nn + z * h0;
      hb0[g2 * 136 + f] = (f16)h0;
    }
    __syncthreads();

    floatx4 accx[6], acch[6];
#pragma unroll
    for (int i = 0; i < 6; ++i) {
      floatx4 z = {0.f, 0.f, 0.f, 0.f}; accx[i] = z; acch[i] = z;
    }
#pragma unroll
    for (int kc = 0; kc < 4; ++kc) {
      f16x8 ax = *(const f16x8*)(hb0 + mm * 136 + kc * 32 + quad * 8);
      f16x8 ah = *(const f16x8*)(hb1 + mm * 136 + kc * 32 + quad * 8);
#pragma unroll
      for (int i = 0; i < 6; ++i) {
        accx[i] = __builtin_amdgcn_mfma_f32_16x16x32_f16(ax, Bs[i * 4 + kc], accx[i], 0, 0, 0);
        acch[i] = __builtin_amdgcn_mfma_f32_16x16x32_f16(ah, B1[i * 4 + kc], acch[i], 0, 0, 0);
      }
    }
    if (quad == 0) {
#pragma unroll
      for (int i = 0; i < 6; ++i) {
        gib[0 * 384 + wave * 96 + i * 16 + mm] = accx[i][0];
        gib[1 * 384 + wave * 96 + i * 16 + mm] = accx[i][1];
        ghb[0 * 384 + wave * 96 + i * 16 + mm] = acch[i][0];
        ghb[1 * 384 + wave * 96 + i * 16 + mm] = acch[i][1];
      }
    }
    __syncthreads();

    {
      float i1r = gib[g2 * 384 + f];
      float i1z = gib[g2 * 384 + 128 + f];
      float i1n = gib[g2 * 384 + 256 + f];
      float hr = ghb[g2 * 384 + f];
      float hz = ghb[g2 * 384 + 128 + f];
      float hn = ghb[g2 * 384 + 256 + f];
      float r = sig_fast(i1r + hr + br1);
      float z = sig_fast(i1z + hz + bz1);
      float nn = tanh_fast(i1n + bni1 + r * (hn + bnh1));
      h1 = (1.0f - z) * nn + z * h1;
      hb1[g2 * 136 + f] = (f16)h1;
    }
    __syncthreads();
  }

  h1s[g2 * 128 + f] = h1;
  __syncthreads();
  if (tid < 2 * C_) {
    int gg = tid / C_, c = tid - gg * C_;
    float s = bc[c];
    const float* wr = Wc + (size_t)c * 128;
    const float* hr = h1s + gg * 128;
    for (int k = 0; k < 128; k += 4) {
      float4 w = *(const float4*)(wr + k);
      s += hr[k] * w.x + hr[k + 1] * w.y + hr[k + 2] * w.z + hr[k + 3] * w.w;
    }
    out[(bid * 2 + gg) * C_ + c] = s;
  }
}

extern "C" void kernel_launch(void* const* d_in, const int* in_sizes, int n_in,
                              void* d_out, int out_size, void* d_ws, size_t ws_size,
                              hipStream_t stream) {
  const float* x    = (const float*)d_in[0];
  const int*   ei   = (const int*)d_in[1];
  const int*   batch= (const int*)d_in[2];
  const float* W1   = (const float*)d_in[3];
  const float* b1   = (const float*)d_in[4];
  const float* W2   = (const float*)d_in[5];
  const float* b2   = (const float*)d_in[6];
  const float* Wih0 = (const float*)d_in[7];
  const float* Whh0 = (const float*)d_in[8];
  const float* bih0 = (const float*)d_in[9];
  const float* bhh0 = (const float*)d_in[10];
  const float* Wih1 = (const float*)d_in[11];
  const float* Whh1 = (const float*)d_in[12];
  const float* bih1 = (const float*)d_in[13];
  const float* bhh1 = (const float*)d_in[14];
  const float* Wc   = (const float*)d_in[15];
  const float* bc   = (const float*)d_in[16];
  float* out = (float*)d_out;

  char* ws = (char*)d_ws;
  f16*   H2    = (f16*)(ws + OFF_H2);
  f16*   G     = (f16*)(ws + OFF_G);   // G1' = dinv*(x*W1); reused as G2 = H1'*W2
  f16*   H1p   = (f16*)(ws + OFF_H1);
  int*   rec   = (int*)(ws + OFF_REC);
  int*   cnt   = (int*)(ws + OFF_CNT);
  float* dinv  = (float*)(ws + OFF_DINV);
  int*   rp    = (int*)(ws + OFF_RP);
  int*   cntG  = (int*)(ws + OFF_CNTG);
  int*   brp   = (int*)(ws + OFF_BRP);
  f16*   Wp    = (f16*)(ws + OFF_WP);
  int*   blist = (int*)(ws + OFF_BLIST);
  f16*   gp    = (f16*)(ws + OFF_GPACK);
  float* part  = (float*)(ws + OFF_PART);

  prep0_kernel<<<352, 1024, 0, stream>>>(ei, batch, cnt, cntG,
                                         W1, W2, Wp, Wih0, Whh0, Wih1, Whh1, gp);
  scan_kernel<<<9, 1024, 0, stream>>>(cnt, rp, dinv, cntG, brp);
  // fused: G1' = dinv*(x@W1) (313 blocks) || CSR fill + blist (128 blocks)
  gxfill_kernel<<<441, 1024, 0, stream>>>(x, Wp, G, dinv, ei, cnt, rec, batch, brp, blist);

  agg_kernel<1><<<20000, 256, 0, stream>>>(G, H1p, rp, rec, dinv, b1);
  gemm_kernel<<<1250, 256, 0, stream>>>(H1p, Wp + 16384, G);
  agg_kernel<0><<<20000, 256, 0, stream>>>(G, H2, rp, rec, dinv, b2);

  pool1_kernel<<<512, 256, 0, stream>>>(H2, brp, blist, part);
  gru_mega<<<16, 256, 0, stream>>>(gp, part, brp, bih0, bhh0, bih1, bhh1, Wc, bc, out);
}

// Round 12
// 284.477 us; speedup vs baseline: 1.0373x; 1.0149x over previous
//
#include <hip/hip_runtime.h>

#define T_ 8
#define N_ 10000
#define E_ 160000
#define G_ 32
#define C_ 10
#define F_ 128

typedef _Float16 f16;
typedef _Float16 f16x2 __attribute__((ext_vector_type(2)));
typedef _Float16 f16x4 __attribute__((ext_vector_type(4)));
typedef _Float16 f16x8 __attribute__((ext_vector_type(8)));
typedef float floatx4 __attribute__((ext_vector_type(4)));

static constexpr int NSL = 16;                    // preproc slices per t
static constexpr int SLICE = E_ / NSL;            // 10000 edges per (t, slice)

// ---------------- workspace layout (bytes) ----------------
static constexpr size_t OFF_H2    = 0;          // f16 [80000][128] layer-2 output (pool input)
static constexpr size_t OFF_G     = 20480000;   // f16 [80000][128] G1' = dinv*(x*W1), reused as G2 = H1'*W2
static constexpr size_t OFF_H1    = 40960000;   // f16 [80000][128] H1' = dinv*relu(layer1)
static constexpr size_t OFF_REC   = 61440000;   // int [T][E] src, grouped by dst
static constexpr size_t OFF_CNT   = 66560000;   // int [T][16][N] slice hist -> slice base (5.12 MB)
static constexpr size_t OFF_DINV  = 71680000;   // float [T][N]
static constexpr size_t OFF_RP    = 72000000;   // int [T][N+1]
static constexpr size_t OFF_CNTG  = 72320032;   // int [T*G]
static constexpr size_t OFF_BRP   = 72321056;   // int [T*G+1]
static constexpr size_t OFF_WP    = 72322112;   // f16 packed W1,W2 (2*16384), 16B-aligned
static constexpr size_t OFF_BLIST = 72387648;   // int [80000]
static constexpr size_t OFF_GPACK = 72707648;   // f16 4*49152 packed GRU weights
static constexpr size_t OFF_PART  = 73100864;   // float [256][8][128] pool partials
static constexpr size_t OFF_DEG   = 74149440;   // int [T][N] summed in-degree (320 KB)
// end ~74.5 MB

// ---------------- fast gates (v_exp_f32 / v_rcp_f32, ~1 ulp) ----------------
__device__ __forceinline__ float sig_fast(float x) {
  return __builtin_amdgcn_rcpf(1.0f + __builtin_amdgcn_exp2f(-1.4426950408889634f * x));
}
__device__ __forceinline__ float tanh_fast(float x) {
  return 1.0f - 2.0f * __builtin_amdgcn_rcpf(1.0f + __builtin_amdgcn_exp2f(2.8853900817779268f * x));
}

// ---------------- fused phase 1: blocks 0..127 = hist (t,s), blocks 128..351 = weight pack ----------------
__global__ __launch_bounds__(1024) void prep0_kernel(const int* __restrict__ ei,
                                                     const int* __restrict__ batch,
                                                     int* __restrict__ cnt,
                                                     int* __restrict__ cntG,
                                                     const float* __restrict__ W1,
                                                     const float* __restrict__ W2,
                                                     f16* __restrict__ Wp,
                                                     const float* __restrict__ A0,
                                                     const float* __restrict__ A1,
                                                     const float* __restrict__ A2,
                                                     const float* __restrict__ A3,
                                                     f16* __restrict__ gp) {
  __shared__ int hL[N_];                        // 40 KB (hist blocks only)
  __shared__ int cL[G_];
  int b = blockIdx.x, tid = threadIdx.x;
  if (b >= 128) {
    // ---- pack role ----
    int idx = (b - 128) * 1024 + tid;           // < 224*1024 = 229376
    if (idx < 32768) {
      const float* W = (idx < 16384) ? W1 : W2;
      int l = idx & 16383;
      int j = l & 7, lane = (l >> 3) & 63, ct = (l >> 9) & 7, kc = (l >> 12) & 3;
      int k = kc * 32 + ((lane >> 4) & 3) * 8 + j;
      int n = ct * 16 + (lane & 15);
      Wp[idx] = (f16)W[k * 128 + n];
    } else {
      int gidx = idx - 32768;                   // < 196608
      int mat = gidx / 49152, l = gidx - mat * 49152;
      int j = l & 7, lane = (l >> 3) & 63, kc = (l >> 9) & 3, nt = l >> 11;
      int k = kc * 32 + ((lane >> 4) & 3) * 8 + j;
      int u = nt * 16 + (lane & 15);
      const float* W = (mat == 0) ? A0 : (mat == 1) ? A1 : (mat == 2) ? A2 : A3;
      gp[gidx] = (f16)W[u * 128 + k];
    }
    return;
  }
  // ---- hist role: one (t, s) slice per block ----
  int t = b & 7, s = b >> 3;                    // XCD-swizzled by t; s in 0..15
  for (int i = tid; i < N_; i += 1024) hL[i] = 0;
  if (tid < G_) cL[tid] = 0;
  __syncthreads();
  const int* dstp = ei + (size_t)t * 2 * E_ + E_ + s * SLICE;
  for (int e4 = tid; e4 < SLICE / 4; e4 += 1024) {
    int4 d = *(const int4*)(dstp + e4 * 4);
    atomicAdd(&hL[d.x], 1); atomicAdd(&hL[d.y], 1);
    atomicAdd(&hL[d.z], 1); atomicAdd(&hL[d.w], 1);
  }
  if (s == 0)
    for (int n = tid; n < N_; n += 1024) atomicAdd(&cL[batch[t * N_ + n]], 1);
  __syncthreads();
  int* cp = cnt + ((size_t)t * NSL + s) * N_;
  for (int i = tid; i < N_; i += 1024) cp[i] = hL[i];
  if (s == 0 && tid < G_) cntG[t * G_ + tid] = cL[tid];
}

// ---------------- scan stage 1: deg[t][n] = sum over slices; dinv (80 blocks) ----------------
__global__ __launch_bounds__(1024) void scan1_kernel(const int* __restrict__ cnt,
                                                     int* __restrict__ deg,
                                                     float* __restrict__ dinv) {
  int b = blockIdx.x, tid = threadIdx.x;
  int t = b & 7, chunk = b >> 3;                // 10 chunks of 1000
  int n = chunk * 1000 + tid;
  if (tid >= 1000) return;
  int d = 0;
#pragma unroll
  for (int s = 0; s < NSL; ++s) d += cnt[((size_t)t * NSL + s) * N_ + n];
  deg[t * N_ + n] = d;
  dinv[t * N_ + n] = rsqrtf((float)d + 1.0f);
}

// ---------------- scan stage 2: per-t prefix of deg -> rp (320 KB only); blk8 -> brp ----------------
__global__ __launch_bounds__(1024) void scan2_kernel(const int* __restrict__ deg,
                                                     int* __restrict__ rp,
                                                     const int* __restrict__ cntG,
                                                     int* __restrict__ brp) {
  __shared__ int wsum[16];
  __shared__ int carry;
  int t = blockIdx.x, tid = threadIdx.x, lane = tid & 63, wid = tid >> 6;
  if (t == 8) {
    int v = (tid < 256) ? cntG[tid] : 0;
    for (int ofs = 1; ofs < 64; ofs <<= 1) {
      int u = __shfl_up(v, ofs);
      if (lane >= ofs) v += u;
    }
    if (lane == 63 && wid < 4) wsum[wid] = v;
    __syncthreads();
    if (tid < 256) {
      int base = 0;
      for (int w = 0; w < wid; ++w) base += wsum[w];
      if (tid == 0) brp[0] = 0;
      brp[tid + 1] = v + base;
    }
    return;
  }
  if (tid == 0) { carry = 0; rp[t * (N_ + 1)] = 0; }
  __syncthreads();
  for (int c0 = 0; c0 < N_; c0 += 1024) {
    int n = c0 + tid;
    int v = (n < N_) ? deg[t * N_ + n] : 0;
    for (int ofs = 1; ofs < 64; ofs <<= 1) {
      int u = __shfl_up(v, ofs);
      if (lane >= ofs) v += u;
    }
    if (lane == 63) wsum[wid] = v;
    __syncthreads();
    if (wid == 0) {
      int w = (lane < 16) ? wsum[lane] : 0;
      for (int ofs = 1; ofs < 16; ofs <<= 1) {
        int u = __shfl_up(w, ofs);
        if (lane >= ofs) w += u;
      }
      if (lane < 16) wsum[lane] = w;
    }
    __syncthreads();
    int base = carry + (wid ? wsum[wid - 1] : 0);
    if (n < N_) rp[t * (N_ + 1) + n + 1] = base + v;
    __syncthreads();
    if (tid == 0) carry += wsum[15];
    __syncthreads();
  }
}

// ---------------- scan stage 3: rebase cnt -> per-slice CSR bases from rp (80 blocks) ----------------
__global__ __launch_bounds__(1024) void scan3_kernel(int* __restrict__ cnt,
                                                     const int* __restrict__ rp) {
  int b = blockIdx.x, tid = threadIdx.x;
  int t = b & 7, chunk = b >> 3;
  int n = chunk * 1000 + tid;
  if (tid >= 1000) return;
  int run = rp[t * (N_ + 1) + n];
#pragma unroll
  for (int s = 0; s < NSL; ++s) {
    size_t idx = ((size_t)t * NSL + s) * N_ + n;
    int v = cnt[idx];
    cnt[idx] = run;
    run += v;
  }
}

// ---------------- fused phase 3: blocks 0..312 = G1'=dinv*(x@W1) (4x64-row tiles),
//                  blocks 313..440 = CSR fill + blist ----------------
__global__ __launch_bounds__(1024) void gxfill_kernel(const float* __restrict__ x,
                                                      const f16* __restrict__ Wp,
                                                      f16* __restrict__ Gout,
                                                      const float* __restrict__ dinv,
                                                      const int* __restrict__ ei,
                                                      const int* __restrict__ base,
                                                      int* __restrict__ rec,
                                                      const int* __restrict__ batch,
                                                      const int* __restrict__ brp,
                                                      int* __restrict__ blist) {
  __shared__ union {
    f16x8 Bp[2048];                             // 32 KB (gemm role)
    struct { int offL[N_]; int cb[G_]; } fl;    // 40.1 KB (fill role)
  } U;
  int b = blockIdx.x, tid = threadIdx.x;
  if (b < 313) {
    // ---- gemm role: rows b*256 + sub*64, sub = tid>>8 ----
    const f16x8* Wv = (const f16x8*)Wp;
    for (int i = tid; i < 2048; i += 1024) U.Bp[i] = Wv[i];
    __syncthreads();
    int stid = tid & 255;
    int sub = tid >> 8;
    int wave = stid >> 6, lane = stid & 63;
    int quad = lane >> 4, m = lane & 15;
    int rowbase = b * 256 + sub * 64 + wave * 16;
    if (rowbase >= 80000) return;
    floatx4 acc[8];
#pragma unroll
    for (int ct = 0; ct < 8; ++ct) { floatx4 z = {0.f, 0.f, 0.f, 0.f}; acc[ct] = z; }
#pragma unroll
    for (int kc = 0; kc < 4; ++kc) {
      const float* Ar = x + (size_t)(rowbase + m) * F_ + kc * 32 + quad * 8;
      float4 lo = *(const float4*)Ar;
      float4 hi = *(const float4*)(Ar + 4);
      f16x8 a;
      a[0] = (f16)lo.x; a[1] = (f16)lo.y; a[2] = (f16)lo.z; a[3] = (f16)lo.w;
      a[4] = (f16)hi.x; a[5] = (f16)hi.y; a[6] = (f16)hi.z; a[7] = (f16)hi.w;
#pragma unroll
      for (int ct = 0; ct < 8; ++ct)
        acc[ct] = __builtin_amdgcn_mfma_f32_16x16x32_f16(a, U.Bp[(kc * 8 + ct) * 64 + lane],
                                                         acc[ct], 0, 0, 0);
    }
    float sv[4];
#pragma unroll
    for (int r = 0; r < 4; ++r) sv[r] = dinv[rowbase + quad * 4 + r];
#pragma unroll
    for (int ct = 0; ct < 8; ++ct) {
      int colc = ct * 16 + m;
#pragma unroll
      for (int r = 0; r < 4; ++r)
        Gout[(size_t)(rowbase + quad * 4 + r) * F_ + colc] = (f16)(acc[ct][r] * sv[r]);
    }
    return;
  }
  // ---- fill role: one (t, s) slice per block ----
  int b2 = b - 313;
  int t = b2 & 7, s = b2 >> 3;
  const int* bp = base + ((size_t)t * NSL + s) * N_;
  for (int i = tid; i < N_; i += 1024) U.fl.offL[i] = bp[i];
  if (s == 0 && tid < G_) U.fl.cb[tid] = brp[t * G_ + tid];
  __syncthreads();
  const int* srcp = ei + (size_t)t * 2 * E_ + s * SLICE;
  const int* dstp = srcp + E_;
  int* rt = rec + (size_t)t * E_;
  for (int e4 = tid; e4 < SLICE / 4; e4 += 1024) {
    int4 sv = *(const int4*)(srcp + e4 * 4);
    int4 dv = *(const int4*)(dstp + e4 * 4);
    int p0 = atomicAdd(&U.fl.offL[dv.x], 1);
    int p1 = atomicAdd(&U.fl.offL[dv.y], 1);
    int p2 = atomicAdd(&U.fl.offL[dv.z], 1);
    int p3 = atomicAdd(&U.fl.offL[dv.w], 1);
    rt[p0] = sv.x; rt[p1] = sv.y; rt[p2] = sv.z; rt[p3] = sv.w;
  }
  if (s == 0) {
    for (int n = tid; n < N_; n += 1024) {
      int g = batch[t * N_ + n];
      int p = atomicAdd(&U.fl.cb[g], 1);
      blist[p] = t * N_ + n;
    }
  }
}

// ---------------- GEMM (f16 A): O = A @ W, MFMA 16x16x32 ----------------
__global__ __launch_bounds__(256) void gemm_kernel(const f16* __restrict__ A,
                                                   const f16* __restrict__ Wp,
                                                   f16* __restrict__ O) {
  __shared__ f16x8 Bp[2048];                    // 32 KB packed W
  const f16x8* Wv = (const f16x8*)Wp;
  for (int i = threadIdx.x; i < 2048; i += 256) Bp[i] = Wv[i];
  __syncthreads();
  int wave = threadIdx.x >> 6, lane = threadIdx.x & 63;
  int quad = lane >> 4, m = lane & 15;
  int rowbase = blockIdx.x * 64 + wave * 16;
  const f16x8* Arow = (const f16x8*)(A + (size_t)(rowbase + m) * F_);
  floatx4 acc[8];
#pragma unroll
  for (int ct = 0; ct < 8; ++ct) { floatx4 z = {0.f, 0.f, 0.f, 0.f}; acc[ct] = z; }
#pragma unroll
  for (int kc = 0; kc < 4; ++kc) {
    f16x8 a = Arow[kc * 4 + quad];
#pragma unroll
    for (int ct = 0; ct < 8; ++ct)
      acc[ct] = __builtin_amdgcn_mfma_f32_16x16x32_f16(a, Bp[(kc * 8 + ct) * 64 + lane],
                                                       acc[ct], 0, 0, 0);
  }
#pragma unroll
  for (int ct = 0; ct < 8; ++ct) {
    int colc = ct * 16 + m;
#pragma unroll
    for (int r = 0; r < 4; ++r)
      O[(size_t)(rowbase + quad * 4 + r) * F_ + colc] = (f16)acc[ct][r];
  }
}

// ---------------- aggregation: plain sums, 3-deep value pipeline ----------------
// s = Σ G'[src] + G'[row];  out = relu(ds·s + b) [· ds if SCALE_OUT]
template <int SCALE_OUT>
__global__ __launch_bounds__(256) void agg_kernel(const f16* __restrict__ X, f16* __restrict__ O,
                                                  const int* __restrict__ rp,
                                                  const int* __restrict__ rec,
                                                  const float* __restrict__ dinv,
                                                  const float* __restrict__ bias) {
  int wave = threadIdx.x >> 6, lane = threadIdx.x & 63;
  int eg = lane >> 4;
  int cb = (lane & 15) * 8;
  int b = blockIdx.x;
  int t = b & 7, i = b >> 3;                    // t-swizzled: per-XCD L2 locality on G slice
  int n = i * 4 + wave;
  int row = t * N_ + n;
  float ds = dinv[row];
  int beg = rp[t * (N_ + 1) + n], end = rp[t * (N_ + 1) + n + 1];
  beg = __builtin_amdgcn_readfirstlane(beg);
  end = __builtin_amdgcn_readfirstlane(end);
  const int* rcb = rec + (size_t)t * E_ + beg + eg;
  const f16* Xt = X + (size_t)t * N_ * F_;

  float s[8] = {0.f, 0.f, 0.f, 0.f, 0.f, 0.f, 0.f, 0.f};
  if (eg == 3) {                                // self-loop term on slot 3
    f16x8 v = *(const f16x8*)(Xt + (size_t)n * F_ + cb);
#pragma unroll
    for (int j = 0; j < 8; ++j) s[j] += (float)v[j];
  }
  int cnt = end - beg;
  int nq = cnt >> 2;
  if (nq > 0) {
    // 4 indices prefetched, 3 value loads in flight
    int rid0 = rcb[0];
    int rid1 = (nq > 1) ? rcb[4] : 0;
    int rid2 = (nq > 2) ? rcb[8] : 0;
    f16x8 vA = *(const f16x8*)(Xt + (size_t)rid0 * F_ + cb);
    f16x8 vB, vC;
    if (nq > 1) vB = *(const f16x8*)(Xt + (size_t)rid1 * F_ + cb);
    if (nq > 2) vC = *(const f16x8*)(Xt + (size_t)rid2 * F_ + cb);
    int ridN = (nq > 3) ? rcb[12] : 0;
    for (int q = 0; q + 3 < nq; ++q) {
      f16x8 vD = *(const f16x8*)(Xt + (size_t)ridN * F_ + cb);
      int ridNN = rcb[(q + 4) * 4];             // ≤3 ints past segment: lands in ws, unused unless valid
#pragma unroll
      for (int j = 0; j < 8; ++j) s[j] += (float)vA[j];
      vA = vB; vB = vC; vC = vD; ridN = ridNN;
    }
#pragma unroll
    for (int j = 0; j < 8; ++j) s[j] += (float)vA[j];
    if (nq > 1) {
#pragma unroll
      for (int j = 0; j < 8; ++j) s[j] += (float)vB[j];
    }
    if (nq > 2) {
#pragma unroll
      for (int j = 0; j < 8; ++j) s[j] += (float)vC[j];
    }
  }
  int rem = cnt & 3;
  if (eg < rem) {                               // tail: slots 0..rem-1
    int rid = rcb[nq * 4];
    f16x8 v = *(const f16x8*)(Xt + (size_t)rid * F_ + cb);
#pragma unroll
    for (int j = 0; j < 8; ++j) s[j] += (float)v[j];
  }
#pragma unroll
  for (int j = 0; j < 8; ++j) {                 // reduce the 4 edge slots
    s[j] += __shfl_xor(s[j], 16);
    s[j] += __shfl_xor(s[j], 32);
  }
  if (eg == 0) {
    float4 b0 = *(const float4*)(bias + cb);
    float4 b1v = *(const float4*)(bias + cb + 4);
    float bb[8] = {b0.x, b0.y, b0.z, b0.w, b1v.x, b1v.y, b1v.z, b1v.w};
    f16x8 o;
#pragma unroll
    for (int j = 0; j < 8; ++j) {
      float v = fmaxf(ds * s[j] + bb[j], 0.0f);
      if (SCALE_OUT) v *= ds;
      o[j] = (f16)v;
    }
    *(f16x8*)(O + (size_t)row * F_ + cb) = o;
  }
}

// ---------------- pool stage 1: one wave per (group, 1/8 slice) -> fp32 partials ----------------
__global__ void pool1_kernel(const f16* __restrict__ H, const int* __restrict__ brp,
                             const int* __restrict__ blist, float* __restrict__ part) {
  int b = blockIdx.x;                           // 512
  int wave = threadIdx.x >> 6, lane = threadIdx.x & 63;
  int idx = b >> 1;                             // t*G+g
  int s = (b & 1) * 4 + wave;                   // 0..7
  int beg = brp[idx], end = brp[idx + 1];
  beg = __builtin_amdgcn_readfirstlane(beg);
  end = __builtin_amdgcn_readfirstlane(end);
  int len = end - beg;
  int lo = beg + (int)(((long long)len * s) >> 3);
  int hi = beg + (int)(((long long)len * (s + 1)) >> 3);
  float a00 = 0.f, a01 = 0.f, a10 = 0.f, a11 = 0.f;
  float a20 = 0.f, a21 = 0.f, a30 = 0.f, a31 = 0.f;
  int e = lo;
  for (; e + 3 < hi; e += 4) {
    int r0 = blist[e], r1 = blist[e + 1], r2 = blist[e + 2], r3 = blist[e + 3];
    f16x2 v0 = *(const f16x2*)(H + (size_t)r0 * F_ + 2 * lane);
    f16x2 v1 = *(const f16x2*)(H + (size_t)r1 * F_ + 2 * lane);
    f16x2 v2 = *(const f16x2*)(H + (size_t)r2 * F_ + 2 * lane);
    f16x2 v3 = *(const f16x2*)(H + (size_t)r3 * F_ + 2 * lane);
    a00 += (float)v0.x; a01 += (float)v0.y;
    a10 += (float)v1.x; a11 += (float)v1.y;
    a20 += (float)v2.x; a21 += (float)v2.y;
    a30 += (float)v3.x; a31 += (float)v3.y;
  }
  for (; e < hi; ++e) {
    int r = blist[e];
    f16x2 v = *(const f16x2*)(H + (size_t)r * F_ + 2 * lane);
    a00 += (float)v.x; a01 += (float)v.y;
  }
  float2 o;
  o.x = (a00 + a10) + (a20 + a30);
  o.y = (a01 + a11) + (a21 + a31);
  *(float2*)(part + ((size_t)idx * 8 + s) * F_ + 2 * lane) = o;
}

// ---------------- mega tail: pool2 + gi0 + 2-layer GRU + final linear (16 blocks) ----------------
__global__ __launch_bounds__(256, 1) void gru_mega(
    const f16* __restrict__ gp, const float* __restrict__ part,
    const int* __restrict__ brp,
    const float* __restrict__ bih0, const float* __restrict__ bhh0,
    const float* __restrict__ bih1, const float* __restrict__ bhh1,
    const float* __restrict__ Wc, const float* __restrict__ bc,
    float* __restrict__ out) {
  __shared__ f16 emb_l[16][136];                // rows r = t*2+g2 for this block's 2 groups
  __shared__ float gib0[16][384];               // gi0 for all 8 t, 2 groups
  __shared__ f16 hb0[16 * 136];
  __shared__ f16 hb1[16 * 136];
  __shared__ float ghb[2 * 384];
  __shared__ float gib[2 * 384];
  __shared__ float h1s[2 * 128];
  int tid = threadIdx.x, wave = tid >> 6, lane = tid & 63;
  int quad = lane >> 4, mm = lane & 15;
  int g2 = tid >> 7, f = tid & 127;
  int bid = blockIdx.x;

  // ---- stage A: reduce pool partials -> mean -> f16 emb ----
  {
    int r = tid >> 4;                           // 0..15 = t*2+g2
    int fb = (tid & 15) * 8;
    int idx = (r >> 1) * G_ + bid * 2 + (r & 1);
    float s[8] = {0.f, 0.f, 0.f, 0.f, 0.f, 0.f, 0.f, 0.f};
#pragma unroll
    for (int k = 0; k < 8; ++k) {
      const float* p = part + ((size_t)idx * 8 + k) * F_ + fb;
      float4 v0 = *(const float4*)p;
      float4 v1 = *(const float4*)(p + 4);
      s[0] += v0.x; s[1] += v0.y; s[2] += v0.z; s[3] += v0.w;
      s[4] += v1.x; s[5] += v1.y; s[6] += v1.z; s[7] += v1.w;
    }
    float d = fmaxf((float)(brp[idx + 1] - brp[idx]), 1.0f);
    f16x8 ev;
#pragma unroll
    for (int j = 0; j < 8; ++j) ev[j] = (f16)(s[j] / d);
    *(f16x8*)(&emb_l[r][fb]) = ev;
  }
  __syncthreads();

  // ---- stage B: gi0 = emb @ Wih0^T, 16 rows x 384 cols, into LDS ----
  {
    floatx4 acc[6];
#pragma unroll
    for (int i = 0; i < 6; ++i) { floatx4 z = {0.f, 0.f, 0.f, 0.f}; acc[i] = z; }
#pragma unroll
    for (int kc = 0; kc < 4; ++kc) {
      f16x8 a = *(const f16x8*)(&emb_l[mm][kc * 32 + quad * 8]);
#pragma unroll
      for (int i = 0; i < 6; ++i) {
        int nt = wave * 6 + i;
        f16x8 bf = *(const f16x8*)(gp + (size_t)((nt * 4 + kc) * 64 + lane) * 8);
        acc[i] = __builtin_amdgcn_mfma_f32_16x16x32_f16(a, bf, acc[i], 0, 0, 0);
      }
    }
#pragma unroll
    for (int i = 0; i < 6; ++i)
#pragma unroll
      for (int r = 0; r < 4; ++r)
        gib0[quad * 4 + r][(wave * 6 + i) * 16 + mm] = acc[i][r];
  }

  // ---- persistent recurrent weight fragments (Whh0, Whh1, Wih1 — all t-invariant) ----
  f16x8 B0[24], B1[24], Bs[24];
  const f16* wih1 = gp + 2 * 49152;
#pragma unroll
  for (int i = 0; i < 6; ++i)
#pragma unroll
    for (int kc = 0; kc < 4; ++kc) {
      size_t off = (size_t)((((wave * 6 + i) * 4 + kc) * 64 + lane)) * 8;
      B0[i * 4 + kc] = *(const f16x8*)(gp + 1 * 49152 + off);
      B1[i * 4 + kc] = *(const f16x8*)(gp + 3 * 49152 + off);
      Bs[i * 4 + kc] = *(const f16x8*)(wih1 + off);
    }
  float br0 = bih0[f] + bhh0[f];
  float bz0 = bih0[128 + f] + bhh0[128 + f];
  float bni0 = bih0[256 + f], bnh0 = bhh0[256 + f];
  float br1 = bih1[f] + bhh1[f];
  float bz1 = bih1[128 + f] + bhh1[128 + f];
  float bni1 = bih1[256 + f], bnh1 = bhh1[256 + f];

  for (int i = tid; i < 16 * 136; i += 256) { hb0[i] = (f16)0.f; hb1[i] = (f16)0.f; }
  float h0 = 0.f, h1 = 0.f;
  __syncthreads();                              // covers gib0 writes + hb inits

  for (int t = 0; t < T_; ++t) {
    const float* gi = &gib0[t * 2 + g2][0];
    float gir = gi[f], giz = gi[128 + f], gin = gi[256 + f];

    floatx4 acc[6];
#pragma unroll
    for (int i = 0; i < 6; ++i) { floatx4 z = {0.f, 0.f, 0.f, 0.f}; acc[i] = z; }
#pragma unroll
    for (int kc = 0; kc < 4; ++kc) {
      f16x8 a = *(const f16x8*)(hb0 + mm * 136 + kc * 32 + quad * 8);
#pragma unroll
      for (int i = 0; i < 6; ++i)
        acc[i] = __builtin_amdgcn_mfma_f32_16x16x32_f16(a, B0[i * 4 + kc], acc[i], 0, 0, 0);
    }
    if (quad == 0) {
#pragma unroll
      for (int i = 0; i < 6; ++i) {
        ghb[0 * 384 + wave * 96 + i * 16 + mm] = acc[i][0];
        ghb[1 * 384 + wave * 96 + i * 16 + mm] = acc[i][1];
      }
    }
    __syncthreads();

    {
      float hr = ghb[g2 * 384 + f];
      float hz = ghb[g2 * 384 + 128 + f];
      float hn = ghb[g2 * 384 + 256 + f];
      float r = sig_fast(gir + hr + br0);
      float z = sig_fast(giz + hz + bz0);
      float nn = tanh_fast(gin + bni0 + r * (hn + bnh0));
      h0 = (1.0f - z) * nn + z * h0;
      hb0[g2 * 136 + f] = (f16)h0;
    }
    __syncthreads();

    floatx4 accx[6], acch[6];
#pragma unroll
    for (int i = 0; i < 6; ++i) {
      floatx4 z = {0.f, 0.f, 0.f, 0.f}; accx[i] = z; acch[i] = z;
    }
#pragma unroll
    for (int kc = 0; kc < 4; ++kc) {
      f16x8 ax = *(const f16x8*)(hb0 + mm * 136 + kc * 32 + quad * 8);
      f16x8 ah = *(const f16x8*)(hb1 + mm * 136 + kc * 32 + quad * 8);
#pragma unroll
      for (int i = 0; i < 6; ++i) {
        accx[i] = __builtin_amdgcn_mfma_f32_16x16x32_f16(ax, Bs[i * 4 + kc], accx[i], 0, 0, 0);
        acch[i] = __builtin_amdgcn_mfma_f32_16x16x32_f16(ah, B1[i * 4 + kc], acch[i], 0, 0, 0);
      }
    }
    if (quad == 0) {
#pragma unroll
      for (int i = 0; i < 6; ++i) {
        gib[0 * 384 + wave * 96 + i * 16 + mm] = accx[i][0];
        gib[1 * 384 + wave * 96 + i * 16 + mm] = accx[i][1];
        ghb[0 * 384 + wave * 96 + i * 16 + mm] = acch[i][0];
        ghb[1 * 384 + wave * 96 + i * 16 + mm] = acch[i][1];
      }
    }
    __syncthreads();

    {
      float i1r = gib[g2 * 384 + f];
      float i1z = gib[g2 * 384 + 128 + f];
      float i1n = gib[g2 * 384 + 256 + f];
      float hr = ghb[g2 * 384 + f];
      float hz = ghb[g2 * 384 + 128 + f];
      float hn = ghb[g2 * 384 + 256 + f];
      float r = sig_fast(i1r + hr + br1);
      float z = sig_fast(i1z + hz + bz1);
      float nn = tanh_fast(i1n + bni1 + r * (hn + bnh1));
      h1 = (1.0f - z) * nn + z * h1;
      hb1[g2 * 136 + f] = (f16)h1;
    }
    __syncthreads();
  }

  h1s[g2 * 128 + f] = h1;
  __syncthreads();
  if (tid < 2 * C_) {
    int gg = tid / C_, c = tid - gg * C_;
    float s = bc[c];
    const float* wr = Wc + (size_t)c * 128;
    const float* hr = h1s + gg * 128;
    for (int k = 0; k < 128; k += 4) {
      float4 w = *(const float4*)(wr + k);
      s += hr[k] * w.x + hr[k + 1] * w.y + hr[k + 2] * w.z + hr[k + 3] * w.w;
    }
    out[(bid * 2 + gg) * C_ + c] = s;
  }
}

extern "C" void kernel_launch(void* const* d_in, const int* in_sizes, int n_in,
                              void* d_out, int out_size, void* d_ws, size_t ws_size,
                              hipStream_t stream) {
  const float* x    = (const float*)d_in[0];
  const int*   ei   = (const int*)d_in[1];
  const int*   batch= (const int*)d_in[2];
  const float* W1   = (const float*)d_in[3];
  const float* b1   = (const float*)d_in[4];
  const float* W2   = (const float*)d_in[5];
  const float* b2   = (const float*)d_in[6];
  const float* Wih0 = (const float*)d_in[7];
  const float* Whh0 = (const float*)d_in[8];
  const float* bih0 = (const float*)d_in[9];
  const float* bhh0 = (const float*)d_in[10];
  const float* Wih1 = (const float*)d_in[11];
  const float* Whh1 = (const float*)d_in[12];
  const float* bih1 = (const float*)d_in[13];
  const float* bhh1 = (const float*)d_in[14];
  const float* Wc   = (const float*)d_in[15];
  const float* bc   = (const float*)d_in[16];
  float* out = (float*)d_out;

  char* ws = (char*)d_ws;
  f16*   H2    = (f16*)(ws + OFF_H2);
  f16*   G     = (f16*)(ws + OFF_G);   // G1' = dinv*(x*W1); reused as G2 = H1'*W2
  f16*   H1p   = (f16*)(ws + OFF_H1);
  int*   rec   = (int*)(ws + OFF_REC);
  int*   cnt   = (int*)(ws + OFF_CNT);
  float* dinv  = (float*)(ws + OFF_DINV);
  int*   rp    = (int*)(ws + OFF_RP);
  int*   cntG  = (int*)(ws + OFF_CNTG);
  int*   brp   = (int*)(ws + OFF_BRP);
  f16*   Wp    = (f16*)(ws + OFF_WP);
  int*   blist = (int*)(ws + OFF_BLIST);
  f16*   gp    = (f16*)(ws + OFF_GPACK);
  float* part  = (float*)(ws + OFF_PART);
  int*   deg   = (int*)(ws + OFF_DEG);

  prep0_kernel<<<352, 1024, 0, stream>>>(ei, batch, cnt, cntG,
                                         W1, W2, Wp, Wih0, Whh0, Wih1, Whh1, gp);
  scan1_kernel<<<80, 1024, 0, stream>>>(cnt, deg, dinv);
  scan2_kernel<<<9, 1024, 0, stream>>>(deg, rp, cntG, brp);
  scan3_kernel<<<80, 1024, 0, stream>>>(cnt, rp);
  // fused: G1' = dinv*(x@W1) (313 blocks) || CSR fill + blist (128 blocks)
  gxfill_kernel<<<441, 1024, 0, stream>>>(x, Wp, G, dinv, ei, cnt, rec, batch, brp, blist);

  agg_kernel<1><<<20000, 256, 0, stream>>>(G, H1p, rp, rec, dinv, b1);
  gemm_kernel<<<1250, 256, 0, stream>>>(H1p, Wp + 16384, G);
  agg_kernel<0><<<20000, 256, 0, stream>>>(G, H2, rp, rec, dinv, b2);

  pool1_kernel<<<512, 256, 0, stream>>>(H2, brp, blist, part);
  gru_mega<<<16, 256, 0, stream>>>(gp, part, brp, bih0, bhh0, bih1, bhh1, Wc, bc, out);
}

// Round 13
// 282.389 us; speedup vs baseline: 1.0449x; 1.0074x over previous
//
#include <hip/hip_runtime.h>

#define T_ 8
#define N_ 10000
#define E_ 160000
#define G_ 32
#define C_ 10
#define F_ 128

typedef _Float16 f16;
typedef _Float16 f16x2 __attribute__((ext_vector_type(2)));
typedef _Float16 f16x4 __attribute__((ext_vector_type(4)));
typedef _Float16 f16x8 __attribute__((ext_vector_type(8)));
typedef float floatx4 __attribute__((ext_vector_type(4)));

static constexpr int NSL = 16;                    // preproc slices per t
static constexpr int SLICE = E_ / NSL;            // 10000 edges per (t, slice)

// ---------------- workspace layout (bytes) ----------------
static constexpr size_t OFF_H2    = 0;          // f16 [80000][128] layer-2 output (pool input)
static constexpr size_t OFF_G     = 20480000;   // f16 [80000][128] G1' = dinv*(x*W1), reused as G2 = H1'*W2
static constexpr size_t OFF_H1    = 40960000;   // f16 [80000][128] H1' = dinv*relu(layer1)
static constexpr size_t OFF_REC   = 61440000;   // int [T][E] src, grouped by dst
static constexpr size_t OFF_CNT   = 66560000;   // int [T][16][N] slice hist -> slice base (5.12 MB)
static constexpr size_t OFF_DINV  = 71680000;   // float [T][N]
static constexpr size_t OFF_RP    = 72000000;   // int [T][N+1]
static constexpr size_t OFF_CNTG  = 72320032;   // int [T*G]
static constexpr size_t OFF_BRP   = 72321056;   // int [T*G+1]
static constexpr size_t OFF_WP    = 72322112;   // f16 packed W1,W2 (2*16384), 16B-aligned
static constexpr size_t OFF_BLIST = 72387648;   // int [80000]
static constexpr size_t OFF_GPACK = 72707648;   // f16 4*49152 packed GRU weights
static constexpr size_t OFF_PART  = 73100864;   // float [256][8][128] pool partials
static constexpr size_t OFF_DEG   = 74149440;   // int [T][N] summed in-degree (320 KB)
// end ~74.5 MB

// ---------------- fast gates (v_exp_f32 / v_rcp_f32, ~1 ulp) ----------------
__device__ __forceinline__ float sig_fast(float x) {
  return __builtin_amdgcn_rcpf(1.0f + __builtin_amdgcn_exp2f(-1.4426950408889634f * x));
}
__device__ __forceinline__ float tanh_fast(float x) {
  return 1.0f - 2.0f * __builtin_amdgcn_rcpf(1.0f + __builtin_amdgcn_exp2f(2.8853900817779268f * x));
}

// ---------------- fused phase 1: blocks 0..127 = hist (t,s), blocks 128..351 = weight pack ----------------
__global__ __launch_bounds__(1024) void prep0_kernel(const int* __restrict__ ei,
                                                     const int* __restrict__ batch,
                                                     int* __restrict__ cnt,
                                                     int* __restrict__ cntG,
                                                     const float* __restrict__ W1,
                                                     const float* __restrict__ W2,
                                                     f16* __restrict__ Wp,
                                                     const float* __restrict__ A0,
                                                     const float* __restrict__ A1,
                                                     const float* __restrict__ A2,
                                                     const float* __restrict__ A3,
                                                     f16* __restrict__ gp) {
  __shared__ int hL[N_];                        // 40 KB (hist blocks only)
  __shared__ int cL[G_];
  int b = blockIdx.x, tid = threadIdx.x;
  if (b >= 128) {
    // ---- pack role ----
    int idx = (b - 128) * 1024 + tid;           // < 224*1024 = 229376
    if (idx < 32768) {
      const float* W = (idx < 16384) ? W1 : W2;
      int l = idx & 16383;
      int j = l & 7, lane = (l >> 3) & 63, ct = (l >> 9) & 7, kc = (l >> 12) & 3;
      int k = kc * 32 + ((lane >> 4) & 3) * 8 + j;
      int n = ct * 16 + (lane & 15);
      Wp[idx] = (f16)W[k * 128 + n];
    } else {
      int gidx = idx - 32768;                   // < 196608
      int mat = gidx / 49152, l = gidx - mat * 49152;
      int j = l & 7, lane = (l >> 3) & 63, kc = (l >> 9) & 3, nt = l >> 11;
      int k = kc * 32 + ((lane >> 4) & 3) * 8 + j;
      int u = nt * 16 + (lane & 15);
      const float* W = (mat == 0) ? A0 : (mat == 1) ? A1 : (mat == 2) ? A2 : A3;
      gp[gidx] = (f16)W[u * 128 + k];
    }
    return;
  }
  // ---- hist role: one (t, s) slice per block ----
  int t = b & 7, s = b >> 3;                    // XCD-swizzled by t; s in 0..15
  for (int i = tid; i < N_; i += 1024) hL[i] = 0;
  if (tid < G_) cL[tid] = 0;
  __syncthreads();
  const int* dstp = ei + (size_t)t * 2 * E_ + E_ + s * SLICE;
  for (int e4 = tid; e4 < SLICE / 4; e4 += 1024) {
    int4 d = *(const int4*)(dstp + e4 * 4);
    atomicAdd(&hL[d.x], 1); atomicAdd(&hL[d.y], 1);
    atomicAdd(&hL[d.z], 1); atomicAdd(&hL[d.w], 1);
  }
  if (s == 0)
    for (int n = tid; n < N_; n += 1024) atomicAdd(&cL[batch[t * N_ + n]], 1);
  __syncthreads();
  int* cp = cnt + ((size_t)t * NSL + s) * N_;
  for (int i = tid; i < N_; i += 1024) cp[i] = hL[i];
  if (s == 0 && tid < G_) cntG[t * G_ + tid] = cL[tid];
}

// ---------------- scan stage 1: deg[t][n] = sum over slices; dinv (80 blocks) ----------------
__global__ __launch_bounds__(1024) void scan1_kernel(const int* __restrict__ cnt,
                                                     int* __restrict__ deg,
                                                     float* __restrict__ dinv) {
  int b = blockIdx.x, tid = threadIdx.x;
  int t = b & 7, chunk = b >> 3;                // 10 chunks of 1000
  int n = chunk * 1000 + tid;
  if (tid >= 1000) return;
  int d = 0;
#pragma unroll
  for (int s = 0; s < NSL; ++s) d += cnt[((size_t)t * NSL + s) * N_ + n];
  deg[t * N_ + n] = d;
  dinv[t * N_ + n] = rsqrtf((float)d + 1.0f);
}

// ---------------- scan stage 2: per-t prefix of deg -> rp (320 KB only); blk8 -> brp ----------------
__global__ __launch_bounds__(1024) void scan2_kernel(const int* __restrict__ deg,
                                                     int* __restrict__ rp,
                                                     const int* __restrict__ cntG,
                                                     int* __restrict__ brp) {
  __shared__ int wsum[16];
  __shared__ int carry;
  int t = blockIdx.x, tid = threadIdx.x, lane = tid & 63, wid = tid >> 6;
  if (t == 8) {
    int v = (tid < 256) ? cntG[tid] : 0;
    for (int ofs = 1; ofs < 64; ofs <<= 1) {
      int u = __shfl_up(v, ofs);
      if (lane >= ofs) v += u;
    }
    if (lane == 63 && wid < 4) wsum[wid] = v;
    __syncthreads();
    if (tid < 256) {
      int base = 0;
      for (int w = 0; w < wid; ++w) base += wsum[w];
      if (tid == 0) brp[0] = 0;
      brp[tid + 1] = v + base;
    }
    return;
  }
  if (tid == 0) { carry = 0; rp[t * (N_ + 1)] = 0; }
  __syncthreads();
  for (int c0 = 0; c0 < N_; c0 += 1024) {
    int n = c0 + tid;
    int v = (n < N_) ? deg[t * N_ + n] : 0;
    for (int ofs = 1; ofs < 64; ofs <<= 1) {
      int u = __shfl_up(v, ofs);
      if (lane >= ofs) v += u;
    }
    if (lane == 63) wsum[wid] = v;
    __syncthreads();
    if (wid == 0) {
      int w = (lane < 16) ? wsum[lane] : 0;
      for (int ofs = 1; ofs < 16; ofs <<= 1) {
        int u = __shfl_up(w, ofs);
        if (lane >= ofs) w += u;
      }
      if (lane < 16) wsum[lane] = w;
    }
    __syncthreads();
    int base = carry + (wid ? wsum[wid - 1] : 0);
    if (n < N_) rp[t * (N_ + 1) + n + 1] = base + v;
    __syncthreads();
    if (tid == 0) carry += wsum[15];
    __syncthreads();
  }
}

// ---------------- scan stage 3: rebase cnt -> per-slice CSR bases from rp (80 blocks) ----------------
__global__ __launch_bounds__(1024) void scan3_kernel(int* __restrict__ cnt,
                                                     const int* __restrict__ rp) {
  int b = blockIdx.x, tid = threadIdx.x;
  int t = b & 7, chunk = b >> 3;
  int n = chunk * 1000 + tid;
  if (tid >= 1000) return;
  int run = rp[t * (N_ + 1) + n];
#pragma unroll
  for (int s = 0; s < NSL; ++s) {
    size_t idx = ((size_t)t * NSL + s) * N_ + n;
    int v = cnt[idx];
    cnt[idx] = run;
    run += v;
  }
}

// ---------------- fused phase 3: blocks 0..312 = G1'=dinv*(x@W1) (4x64-row tiles),
//                  blocks 313..440 = CSR fill + blist ----------------
__global__ __launch_bounds__(1024) void gxfill_kernel(const float* __restrict__ x,
                                                      const f16* __restrict__ Wp,
                                                      f16* __restrict__ Gout,
                                                      const float* __restrict__ dinv,
                                                      const int* __restrict__ ei,
                                                      const int* __restrict__ base,
                                                      int* __restrict__ rec,
                                                      const int* __restrict__ batch,
                                                      const int* __restrict__ brp,
                                                      int* __restrict__ blist) {
  __shared__ union {
    f16x8 Bp[2048];                             // 32 KB (gemm role)
    struct { int offL[N_]; int cb[G_]; } fl;    // 40.1 KB (fill role)
  } U;
  int b = blockIdx.x, tid = threadIdx.x;
  if (b < 313) {
    // ---- gemm role: rows b*256 + sub*64, sub = tid>>8 ----
    const f16x8* Wv = (const f16x8*)Wp;
    for (int i = tid; i < 2048; i += 1024) U.Bp[i] = Wv[i];
    __syncthreads();
    int stid = tid & 255;
    int sub = tid >> 8;
    int wave = stid >> 6, lane = stid & 63;
    int quad = lane >> 4, m = lane & 15;
    int rowbase = b * 256 + sub * 64 + wave * 16;
    if (rowbase >= 80000) return;
    floatx4 acc[8];
#pragma unroll
    for (int ct = 0; ct < 8; ++ct) { floatx4 z = {0.f, 0.f, 0.f, 0.f}; acc[ct] = z; }
#pragma unroll
    for (int kc = 0; kc < 4; ++kc) {
      const float* Ar = x + (size_t)(rowbase + m) * F_ + kc * 32 + quad * 8;
      float4 lo = *(const float4*)Ar;
      float4 hi = *(const float4*)(Ar + 4);
      f16x8 a;
      a[0] = (f16)lo.x; a[1] = (f16)lo.y; a[2] = (f16)lo.z; a[3] = (f16)lo.w;
      a[4] = (f16)hi.x; a[5] = (f16)hi.y; a[6] = (f16)hi.z; a[7] = (f16)hi.w;
#pragma unroll
      for (int ct = 0; ct < 8; ++ct)
        acc[ct] = __builtin_amdgcn_mfma_f32_16x16x32_f16(a, U.Bp[(kc * 8 + ct) * 64 + lane],
                                                         acc[ct], 0, 0, 0);
    }
    float sv[4];
#pragma unroll
    for (int r = 0; r < 4; ++r) sv[r] = dinv[rowbase + quad * 4 + r];
#pragma unroll
    for (int ct = 0; ct < 8; ++ct) {
      int colc = ct * 16 + m;
#pragma unroll
      for (int r = 0; r < 4; ++r)
        Gout[(size_t)(rowbase + quad * 4 + r) * F_ + colc] = (f16)(acc[ct][r] * sv[r]);
    }
    return;
  }
  // ---- fill role: one (t, s) slice per block ----
  int b2 = b - 313;
  int t = b2 & 7, s = b2 >> 3;
  const int* bp = base + ((size_t)t * NSL + s) * N_;
  for (int i = tid; i < N_; i += 1024) U.fl.offL[i] = bp[i];
  if (s == 0 && tid < G_) U.fl.cb[tid] = brp[t * G_ + tid];
  __syncthreads();
  const int* srcp = ei + (size_t)t * 2 * E_ + s * SLICE;
  const int* dstp = srcp + E_;
  int* rt = rec + (size_t)t * E_;
  for (int e4 = tid; e4 < SLICE / 4; e4 += 1024) {
    int4 sv = *(const int4*)(srcp + e4 * 4);
    int4 dv = *(const int4*)(dstp + e4 * 4);
    int p0 = atomicAdd(&U.fl.offL[dv.x], 1);
    int p1 = atomicAdd(&U.fl.offL[dv.y], 1);
    int p2 = atomicAdd(&U.fl.offL[dv.z], 1);
    int p3 = atomicAdd(&U.fl.offL[dv.w], 1);
    rt[p0] = sv.x; rt[p1] = sv.y; rt[p2] = sv.z; rt[p3] = sv.w;
  }
  if (s == 0) {
    for (int n = tid; n < N_; n += 1024) {
      int g = batch[t * N_ + n];
      int p = atomicAdd(&U.fl.cb[g], 1);
      blist[p] = t * N_ + n;
    }
  }
}

// ---------------- GEMM (f16 A): O = A @ W, MFMA 16x16x32 ----------------
__global__ __launch_bounds__(256) void gemm_kernel(const f16* __restrict__ A,
                                                   const f16* __restrict__ Wp,
                                                   f16* __restrict__ O) {
  __shared__ f16x8 Bp[2048];                    // 32 KB packed W
  const f16x8* Wv = (const f16x8*)Wp;
  for (int i = threadIdx.x; i < 2048; i += 256) Bp[i] = Wv[i];
  __syncthreads();
  int wave = threadIdx.x >> 6, lane = threadIdx.x & 63;
  int quad = lane >> 4, m = lane & 15;
  int rowbase = blockIdx.x * 64 + wave * 16;
  const f16x8* Arow = (const f16x8*)(A + (size_t)(rowbase + m) * F_);
  floatx4 acc[8];
#pragma unroll
  for (int ct = 0; ct < 8; ++ct) { floatx4 z = {0.f, 0.f, 0.f, 0.f}; acc[ct] = z; }
#pragma unroll
  for (int kc = 0; kc < 4; ++kc) {
    f16x8 a = Arow[kc * 4 + quad];
#pragma unroll
    for (int ct = 0; ct < 8; ++ct)
      acc[ct] = __builtin_amdgcn_mfma_f32_16x16x32_f16(a, Bp[(kc * 8 + ct) * 64 + lane],
                                                       acc[ct], 0, 0, 0);
  }
#pragma unroll
  for (int ct = 0; ct < 8; ++ct) {
    int colc = ct * 16 + m;
#pragma unroll
    for (int r = 0; r < 4; ++r)
      O[(size_t)(rowbase + quad * 4 + r) * F_ + colc] = (f16)acc[ct][r];
  }
}

// ---------------- aggregation: plain sums, 4-deep value pipeline, 5-deep idx prefetch ----------------
// s = Σ G'[src] + G'[row];  out = relu(ds·s + b) [· ds if SCALE_OUT]
template <int SCALE_OUT>
__global__ __launch_bounds__(256) void agg_kernel(const f16* __restrict__ X, f16* __restrict__ O,
                                                  const int* __restrict__ rp,
                                                  const int* __restrict__ rec,
                                                  const float* __restrict__ dinv,
                                                  const float* __restrict__ bias) {
  int wave = threadIdx.x >> 6, lane = threadIdx.x & 63;
  int eg = lane >> 4;
  int cb = (lane & 15) * 8;
  int b = blockIdx.x;
  int t = b & 7, i = b >> 3;                    // t-swizzled: per-XCD L2 locality on G slice
  int n = i * 4 + wave;
  int row = t * N_ + n;
  float ds = dinv[row];
  int beg = rp[t * (N_ + 1) + n], end = rp[t * (N_ + 1) + n + 1];
  beg = __builtin_amdgcn_readfirstlane(beg);
  end = __builtin_amdgcn_readfirstlane(end);
  const int* rcb = rec + (size_t)t * E_ + beg + eg;
  const f16* Xt = X + (size_t)t * N_ * F_;

  float s[8] = {0.f, 0.f, 0.f, 0.f, 0.f, 0.f, 0.f, 0.f};
  if (eg == 3) {                                // self-loop term on slot 3
    f16x8 v = *(const f16x8*)(Xt + (size_t)n * F_ + cb);
#pragma unroll
    for (int j = 0; j < 8; ++j) s[j] += (float)v[j];
  }
  int cnt = end - beg;
  int nq = cnt >> 2;
  if (nq > 0) {
    // 5 indices prefetched, 4 value loads in flight (covers modal nq=4 fully)
    int rid0 = rcb[0];
    int rid1 = (nq > 1) ? rcb[4] : 0;
    int rid2 = (nq > 2) ? rcb[8] : 0;
    int rid3 = (nq > 3) ? rcb[12] : 0;
    f16x8 vA = *(const f16x8*)(Xt + (size_t)rid0 * F_ + cb);
    f16x8 vB, vC, vD;
    if (nq > 1) vB = *(const f16x8*)(Xt + (size_t)rid1 * F_ + cb);
    if (nq > 2) vC = *(const f16x8*)(Xt + (size_t)rid2 * F_ + cb);
    if (nq > 3) vD = *(const f16x8*)(Xt + (size_t)rid3 * F_ + cb);
    int ridN = (nq > 4) ? rcb[16] : 0;
    for (int q = 0; q + 4 < nq; ++q) {
      f16x8 vE = *(const f16x8*)(Xt + (size_t)ridN * F_ + cb);
      int ridNN = rcb[(q + 5) * 4];             // ≤4 ints past segment: lands in ws, unused unless valid
#pragma unroll
      for (int j = 0; j < 8; ++j) s[j] += (float)vA[j];
      vA = vB; vB = vC; vC = vD; vD = vE; ridN = ridNN;
    }
#pragma unroll
    for (int j = 0; j < 8; ++j) s[j] += (float)vA[j];
    if (nq > 1) {
#pragma unroll
      for (int j = 0; j < 8; ++j) s[j] += (float)vB[j];
    }
    if (nq > 2) {
#pragma unroll
      for (int j = 0; j < 8; ++j) s[j] += (float)vC[j];
    }
    if (nq > 3) {
#pragma unroll
      for (int j = 0; j < 8; ++j) s[j] += (float)vD[j];
    }
  }
  int rem = cnt & 3;
  if (eg < rem) {                               // tail: slots 0..rem-1
    int rid = rcb[nq * 4];
    f16x8 v = *(const f16x8*)(Xt + (size_t)rid * F_ + cb);
#pragma unroll
    for (int j = 0; j < 8; ++j) s[j] += (float)v[j];
  }
#pragma unroll
  for (int j = 0; j < 8; ++j) {                 // reduce the 4 edge slots
    s[j] += __shfl_xor(s[j], 16);
    s[j] += __shfl_xor(s[j], 32);
  }
  if (eg == 0) {
    float4 b0 = *(const float4*)(bias + cb);
    float4 b1v = *(const float4*)(bias + cb + 4);
    float bb[8] = {b0.x, b0.y, b0.z, b0.w, b1v.x, b1v.y, b1v.z, b1v.w};
    f16x8 o;
#pragma unroll
    for (int j = 0; j < 8; ++j) {
      float v = fmaxf(ds * s[j] + bb[j], 0.0f);
      if (SCALE_OUT) v *= ds;
      o[j] = (f16)v;
    }
    *(f16x8*)(O + (size_t)row * F_ + cb) = o;
  }
}

// ---------------- pool stage 1: one wave per (group, 1/8 slice) -> fp32 partials ----------------
__global__ void pool1_kernel(const f16* __restrict__ H, const int* __restrict__ brp,
                             const int* __restrict__ blist, float* __restrict__ part) {
  int b = blockIdx.x;                           // 512
  int wave = threadIdx.x >> 6, lane = threadIdx.x & 63;
  int idx = b >> 1;                             // t*G+g
  int s = (b & 1) * 4 + wave;                   // 0..7
  int beg = brp[idx], end = brp[idx + 1];
  beg = __builtin_amdgcn_readfirstlane(beg);
  end = __builtin_amdgcn_readfirstlane(end);
  int len = end - beg;
  int lo = beg + (int)(((long long)len * s) >> 3);
  int hi = beg + (int)(((long long)len * (s + 1)) >> 3);
  float a00 = 0.f, a01 = 0.f, a10 = 0.f, a11 = 0.f;
  float a20 = 0.f, a21 = 0.f, a30 = 0.f, a31 = 0.f;
  int e = lo;
  for (; e + 3 < hi; e += 4) {
    int r0 = blist[e], r1 = blist[e + 1], r2 = blist[e + 2], r3 = blist[e + 3];
    f16x2 v0 = *(const f16x2*)(H + (size_t)r0 * F_ + 2 * lane);
    f16x2 v1 = *(const f16x2*)(H + (size_t)r1 * F_ + 2 * lane);
    f16x2 v2 = *(const f16x2*)(H + (size_t)r2 * F_ + 2 * lane);
    f16x2 v3 = *(const f16x2*)(H + (size_t)r3 * F_ + 2 * lane);
    a00 += (float)v0.x; a01 += (float)v0.y;
    a10 += (float)v1.x; a11 += (float)v1.y;
    a20 += (float)v2.x; a21 += (float)v2.y;
    a30 += (float)v3.x; a31 += (float)v3.y;
  }
  for (; e < hi; ++e) {
    int r = blist[e];
    f16x2 v = *(const f16x2*)(H + (size_t)r * F_ + 2 * lane);
    a00 += (float)v.x; a01 += (float)v.y;
  }
  float2 o;
  o.x = (a00 + a10) + (a20 + a30);
  o.y = (a01 + a11) + (a21 + a31);
  *(float2*)(part + ((size_t)idx * 8 + s) * F_ + 2 * lane) = o;
}

// ---------------- mega tail: pool2 + gi0 + 2-layer GRU + final linear (16 blocks) ----------------
__global__ __launch_bounds__(256, 1) void gru_mega(
    const f16* __restrict__ gp, const float* __restrict__ part,
    const int* __restrict__ brp,
    const float* __restrict__ bih0, const float* __restrict__ bhh0,
    const float* __restrict__ bih1, const float* __restrict__ bhh1,
    const float* __restrict__ Wc, const float* __restrict__ bc,
    float* __restrict__ out) {
  __shared__ f16 emb_l[16][136];                // rows r = t*2+g2 for this block's 2 groups
  __shared__ float gib0[16][384];               // gi0 for all 8 t, 2 groups
  __shared__ f16 hb0[16 * 136];
  __shared__ f16 hb1[16 * 136];
  __shared__ float ghb[2 * 384];
  __shared__ float gib[2 * 384];
  __shared__ float h1s[2 * 128];
  int tid = threadIdx.x, wave = tid >> 6, lane = tid & 63;
  int quad = lane >> 4, mm = lane & 15;
  int g2 = tid >> 7, f = tid & 127;
  int bid = blockIdx.x;

  // ---- stage A: reduce pool partials -> mean -> f16 emb ----
  {
    int r = tid >> 4;                           // 0..15 = t*2+g2
    int fb = (tid & 15) * 8;
    int idx = (r >> 1) * G_ + bid * 2 + (r & 1);
    float s[8] = {0.f, 0.f, 0.f, 0.f, 0.f, 0.f, 0.f, 0.f};
#pragma unroll
    for (int k = 0; k < 8; ++k) {
      const float* p = part + ((size_t)idx * 8 + k) * F_ + fb;
      float4 v0 = *(const float4*)p;
      float4 v1 = *(const float4*)(p + 4);
      s[0] += v0.x; s[1] += v0.y; s[2] += v0.z; s[3] += v0.w;
      s[4] += v1.x; s[5] += v1.y; s[6] += v1.z; s[7] += v1.w;
    }
    float d = fmaxf((float)(brp[idx + 1] - brp[idx]), 1.0f);
    f16x8 ev;
#pragma unroll
    for (int j = 0; j < 8; ++j) ev[j] = (f16)(s[j] / d);
    *(f16x8*)(&emb_l[r][fb]) = ev;
  }
  __syncthreads();

  // ---- stage B: gi0 = emb @ Wih0^T, 16 rows x 384 cols, into LDS ----
  {
    floatx4 acc[6];
#pragma unroll
    for (int i = 0; i < 6; ++i) { floatx4 z = {0.f, 0.f, 0.f, 0.f}; acc[i] = z; }
#pragma unroll
    for (int kc = 0; kc < 4; ++kc) {
      f16x8 a = *(const f16x8*)(&emb_l[mm][kc * 32 + quad * 8]);
#pragma unroll
      for (int i = 0; i < 6; ++i) {
        int nt = wave * 6 + i;
        f16x8 bf = *(const f16x8*)(gp + (size_t)((nt * 4 + kc) * 64 + lane) * 8);
        acc[i] = __builtin_amdgcn_mfma_f32_16x16x32_f16(a, bf, acc[i], 0, 0, 0);
      }
    }
#pragma unroll
    for (int i = 0; i < 6; ++i)
#pragma unroll
      for (int r = 0; r < 4; ++r)
        gib0[quad * 4 + r][(wave * 6 + i) * 16 + mm] = acc[i][r];
  }

  // ---- persistent recurrent weight fragments (Whh0, Whh1, Wih1 — all t-invariant) ----
  f16x8 B0[24], B1[24], Bs[24];
  const f16* wih1 = gp + 2 * 49152;
#pragma unroll
  for (int i = 0; i < 6; ++i)
#pragma unroll
    for (int kc = 0; kc < 4; ++kc) {
      size_t off = (size_t)((((wave * 6 + i) * 4 + kc) * 64 + lane)) * 8;
      B0[i * 4 + kc] = *(const f16x8*)(gp + 1 * 49152 + off);
      B1[i * 4 + kc] = *(const f16x8*)(gp + 3 * 49152 + off);
      Bs[i * 4 + kc] = *(const f16x8*)(wih1 + off);
    }
  float br0 = bih0[f] + bhh0[f];
  float bz0 = bih0[128 + f] + bhh0[128 + f];
  float bni0 = bih0[256 + f], bnh0 = bhh0[256 + f];
  float br1 = bih1[f] + bhh1[f];
  float bz1 = bih1[128 + f] + bhh1[128 + f];
  float bni1 = bih1[256 + f], bnh1 = bhh1[256 + f];

  for (int i = tid; i < 16 * 136; i += 256) { hb0[i] = (f16)0.f; hb1[i] = (f16)0.f; }
  float h0 = 0.f, h1 = 0.f;
  __syncthreads();                              // covers gib0 writes + hb inits

  for (int t = 0; t < T_; ++t) {
    const float* gi = &gib0[t * 2 + g2][0];
    float gir = gi[f], giz = gi[128 + f], gin = gi[256 + f];

    floatx4 acc[6];
#pragma unroll
    for (int i = 0; i < 6; ++i) { floatx4 z = {0.f, 0.f, 0.f, 0.f}; acc[i] = z; }
#pragma unroll
    for (int kc = 0; kc < 4; ++kc) {
      f16x8 a = *(const f16x8*)(hb0 + mm * 136 + kc * 32 + quad * 8);
#pragma unroll
      for (int i = 0; i < 6; ++i)
        acc[i] = __builtin_amdgcn_mfma_f32_16x16x32_f16(a, B0[i * 4 + kc], acc[i], 0, 0, 0);
    }
    if (quad == 0) {
#pragma unroll
      for (int i = 0; i < 6; ++i) {
        ghb[0 * 384 + wave * 96 + i * 16 + mm] = acc[i][0];
        ghb[1 * 384 + wave * 96 + i * 16 + mm] = acc[i][1];
      }
    }
    __syncthreads();

    {
      float hr = ghb[g2 * 384 + f];
      float hz = ghb[g2 * 384 + 128 + f];
      float hn = ghb[g2 * 384 + 256 + f];
      float r = sig_fast(gir + hr + br0);
      float z = sig_fast(giz + hz + bz0);
      float nn = tanh_fast(gin + bni0 + r * (hn + bnh0));
      h0 = (1.0f - z) * nn + z * h0;
      hb0[g2 * 136 + f] = (f16)h0;
    }
    __syncthreads();

    floatx4 accx[6], acch[6];
#pragma unroll
    for (int i = 0; i < 6; ++i) {
      floatx4 z = {0.f, 0.f, 0.f, 0.f}; accx[i] = z; acch[i] = z;
    }
#pragma unroll
    for (int kc = 0; kc < 4; ++kc) {
      f16x8 ax = *(const f16x8*)(hb0 + mm * 136 + kc * 32 + quad * 8);
      f16x8 ah = *(const f16x8*)(hb1 + mm * 136 + kc * 32 + quad * 8);
#pragma unroll
      for (int i = 0; i < 6; ++i) {
        accx[i] = __builtin_amdgcn_mfma_f32_16x16x32_f16(ax, Bs[i * 4 + kc], accx[i], 0, 0, 0);
        acch[i] = __builtin_amdgcn_mfma_f32_16x16x32_f16(ah, B1[i * 4 + kc], acch[i], 0, 0, 0);
      }
    }
    if (quad == 0) {
#pragma unroll
      for (int i = 0; i < 6; ++i) {
        gib[0 * 384 + wave * 96 + i * 16 + mm] = accx[i][0];
        gib[1 * 384 + wave * 96 + i * 16 + mm] = accx[i][1];
        ghb[0 * 384 + wave * 96 + i * 16 + mm] = acch[i][0];
        ghb[1 * 384 + wave * 96 + i * 16 + mm] = acch[i][1];
      }
    }
    __syncthreads();

    {
      float i1r = gib[g2 * 384 + f];
      float i1z = gib[g2 * 384 + 128 + f];
      float i1n = gib[g2 * 384 + 256 + f];
      float hr = ghb[g2 * 384 + f];
      float hz = ghb[g2 * 384 + 128 + f];
      float hn = ghb[g2 * 384 + 256 + f];
      float r = sig_fast(i1r + hr + br1);
      float z = sig_fast(i1z + hz + bz1);
      float nn = tanh_fast(i1n + bni1 + r * (hn + bnh1));
      h1 = (1.0f - z) * nn + z * h1;
      hb1[g2 * 136 + f] = (f16)h1;
    }
    __syncthreads();
  }

  h1s[g2 * 128 + f] = h1;
  __syncthreads();
  if (tid < 2 * C_) {
    int gg = tid / C_, c = tid - gg * C_;
    float s = bc[c];
    const float* wr = Wc + (size_t)c * 128;
    const float* hr = h1s + gg * 128;
    for (int k = 0; k < 128; k += 4) {
      float4 w = *(const float4*)(wr + k);
      s += hr[k] * w.x + hr[k + 1] * w.y + hr[k + 2] * w.z + hr[k + 3] * w.w;
    }
    out[(bid * 2 + gg) * C_ + c] = s;
  }
}

extern "C" void kernel_launch(void* const* d_in, const int* in_sizes, int n_in,
                              void* d_out, int out_size, void* d_ws, size_t ws_size,
                              hipStream_t stream) {
  const float* x    = (const float*)d_in[0];
  const int*   ei   = (const int*)d_in[1];
  const int*   batch= (const int*)d_in[2];
  const float* W1   = (const float*)d_in[3];
  const float* b1   = (const float*)d_in[4];
  const float* W2   = (const float*)d_in[5];
  const float* b2   = (const float*)d_in[6];
  const float* Wih0 = (const float*)d_in[7];
  const float* Whh0 = (const float*)d_in[8];
  const float* bih0 = (const float*)d_in[9];
  const float* bhh0 = (const float*)d_in[10];
  const float* Wih1 = (const float*)d_in[11];
  const float* Whh1 = (const float*)d_in[12];
  const float* bih1 = (const float*)d_in[13];
  const float* bhh1 = (const float*)d_in[14];
  const float* Wc   = (const float*)d_in[15];
  const float* bc   = (const float*)d_in[16];
  float* out = (float*)d_out;

  char* ws = (char*)d_ws;
  f16*   H2    = (f16*)(ws + OFF_H2);
  f16*   G     = (f16*)(ws + OFF_G);   // G1' = dinv*(x*W1); reused as G2 = H1'*W2
  f16*   H1p   = (f16*)(ws + OFF_H1);
  int*   rec   = (int*)(ws + OFF_REC);
  int*   cnt   = (int*)(ws + OFF_CNT);
  float* dinv  = (float*)(ws + OFF_DINV);
  int*   rp    = (int*)(ws + OFF_RP);
  int*   cntG  = (int*)(ws + OFF_CNTG);
  int*   brp   = (int*)(ws + OFF_BRP);
  f16*   Wp    = (f16*)(ws + OFF_WP);
  int*   blist = (int*)(ws + OFF_BLIST);
  f16*   gp    = (f16*)(ws + OFF_GPACK);
  float* part  = (float*)(ws + OFF_PART);
  int*   deg   = (int*)(ws + OFF_DEG);

  prep0_kernel<<<352, 1024, 0, stream>>>(ei, batch, cnt, cntG,
                                         W1, W2, Wp, Wih0, Whh0, Wih1, Whh1, gp);
  scan1_kernel<<<80, 1024, 0, stream>>>(cnt, deg, dinv);
  scan2_kernel<<<9, 1024, 0, stream>>>(deg, rp, cntG, brp);
  scan3_kernel<<<80, 1024, 0, stream>>>(cnt, rp);
  // fused: G1' = dinv*(x@W1) (313 blocks) || CSR fill + blist (128 blocks)
  gxfill_kernel<<<441, 1024, 0, stream>>>(x, Wp, G, dinv, ei, cnt, rec, batch, brp, blist);

  agg_kernel<1><<<20000, 256, 0, stream>>>(G, H1p, rp, rec, dinv, b1);
  gemm_kernel<<<1250, 256, 0, stream>>>(H1p, Wp + 16384, G);
  agg_kernel<0><<<20000, 256, 0, stream>>>(G, H2, rp, rec, dinv, b2);

  pool1_kernel<<<512, 256, 0, stream>>>(H2, brp, blist, part);
  gru_mega<<<16, 256, 0, stream>>>(gp, part, brp, bih0, bhh0, bih1, bhh1, Wc, bc, out);
}